// Round 1
// baseline (4915.459 us; speedup 1.0000x reference)
//
#include <hip/hip_runtime.h>
#include <hip/hip_bf16.h>

#define BB 4
#define TT 1024
#define DD 1024
#define HH 16
#define DKK 64
#define FFF 4096
// rows = BB*TT = 4096

// ---------------- masked softmax over d (axis -2) + transpose to (D, H*DK) ----------------
__global__ __launch_bounds__(256) void k_softmax_w(const float* __restrict__ W, float* __restrict__ Wt) {
  int col = blockIdx.x;           // h*64 + k
  int h = col >> 6, k = col & 63;
  int tid = threadIdx.x;
  const float* w = W + ((size_t)h * DD) * DKK + k;
  __shared__ float red[256];
  float m = -1e30f;
  for (int d = k + tid; d < DD; d += 256) m = fmaxf(m, w[(size_t)d * DKK]);
  red[tid] = m; __syncthreads();
  for (int s = 128; s > 0; s >>= 1) { if (tid < s) red[tid] = fmaxf(red[tid], red[tid + s]); __syncthreads(); }
  m = red[0]; __syncthreads();
  float sum = 0.f;
  for (int d = k + tid; d < DD; d += 256) sum += __expf(w[(size_t)d * DKK] - m);
  red[tid] = sum; __syncthreads();
  for (int s = 128; s > 0; s >>= 1) { if (tid < s) red[tid] += red[tid + s]; __syncthreads(); }
  float inv = 1.f / red[0];
  for (int d = tid; d < DD; d += 256) {
    float v = (d >= k) ? __expf(w[(size_t)d * DKK] - m) * inv : 0.f;
    Wt[(size_t)d * (HH * DKK) + col] = v;
  }
}

// ---------------- reorder (H, D, DK) -> (D, H*DK) ----------------
__global__ __launch_bounds__(256) void k_reorder_w(const float* __restrict__ W, float* __restrict__ Wt) {
  int idx = blockIdx.x * 256 + threadIdx.x;   // over H*D*DK = 1M
  int k = idx & 63;
  int d = (idx >> 6) & 1023;
  int h = idx >> 16;
  Wt[(size_t)d * (HH * DKK) + h * DKK + k] = W[idx];
}

// ---------------- C(MxN) = A(MxK) * B(KxN), all row-major ----------------
__global__ __launch_bounds__(256) void k_gemm_nn(const float* __restrict__ A, const float* __restrict__ Bm,
                                                 float* __restrict__ C, int M, int N, int K) {
  __shared__ float As[64][17];
  __shared__ float Bs[16][65];
  int row0 = blockIdx.y << 6, col0 = blockIdx.x << 6;
  int tid = threadIdx.x;
  int tr = tid >> 4, tc = tid & 15;
  float acc[4][4] = {};
  for (int k0 = 0; k0 < K; k0 += 16) {
    for (int i = tid; i < 1024; i += 256) {
      int r = i >> 4, c = i & 15;
      As[r][c] = A[(size_t)(row0 + r) * K + k0 + c];
    }
    for (int i = tid; i < 1024; i += 256) {
      int r = i >> 6, c = i & 63;
      Bs[r][c] = Bm[(size_t)(k0 + r) * N + col0 + c];
    }
    __syncthreads();
    #pragma unroll
    for (int kk = 0; kk < 16; ++kk) {
      float a[4], b[4];
      #pragma unroll
      for (int i = 0; i < 4; ++i) a[i] = As[tr * 4 + i][kk];
      #pragma unroll
      for (int j = 0; j < 4; ++j) b[j] = Bs[kk][tc * 4 + j];
      #pragma unroll
      for (int i = 0; i < 4; ++i)
        #pragma unroll
        for (int j = 0; j < 4; ++j) acc[i][j] += a[i] * b[j];
    }
    __syncthreads();
  }
  #pragma unroll
  for (int i = 0; i < 4; ++i)
    #pragma unroll
    for (int j = 0; j < 4; ++j)
      C[(size_t)(row0 + tr * 4 + i) * N + col0 + tc * 4 + j] = acc[i][j];
}

// ---------------- C(MxN) = A(MxK) * B(NxK)^T + bias, optional relu ----------------
__global__ __launch_bounds__(256) void k_gemm_nt(const float* __restrict__ A, const float* __restrict__ Bm,
                                                 const float* __restrict__ bias, float* __restrict__ C,
                                                 int M, int N, int K, int relu) {
  __shared__ float As[64][17];
  __shared__ float Bs[64][17];
  int row0 = blockIdx.y << 6, col0 = blockIdx.x << 6;
  int tid = threadIdx.x;
  int tr = tid >> 4, tc = tid & 15;
  float acc[4][4] = {};
  for (int k0 = 0; k0 < K; k0 += 16) {
    for (int i = tid; i < 1024; i += 256) {
      int r = i >> 4, c = i & 15;
      As[r][c] = A[(size_t)(row0 + r) * K + k0 + c];
      Bs[r][c] = Bm[(size_t)(col0 + r) * K + k0 + c];
    }
    __syncthreads();
    #pragma unroll
    for (int kk = 0; kk < 16; ++kk) {
      float a[4], b[4];
      #pragma unroll
      for (int i = 0; i < 4; ++i) a[i] = As[tr * 4 + i][kk];
      #pragma unroll
      for (int j = 0; j < 4; ++j) b[j] = Bs[tc * 4 + j][kk];
      #pragma unroll
      for (int i = 0; i < 4; ++i)
        #pragma unroll
        for (int j = 0; j < 4; ++j) acc[i][j] += a[i] * b[j];
    }
    __syncthreads();
  }
  #pragma unroll
  for (int i = 0; i < 4; ++i)
    #pragma unroll
    for (int j = 0; j < 4; ++j) {
      int cc = col0 + tc * 4 + j;
      float v = acc[i][j] + (bias ? bias[cc] : 0.f);
      if (relu) v = fmaxf(v, 0.f);
      C[(size_t)(row0 + tr * 4 + i) * N + cc] = v;
    }
}

// ---------------- attention pass 1: per-column (over t) max & sum of exp ----------------
// Q,K layout: (B, T, H, DK). scores[t][s] = dot(Q[t],K[s]) * 0.125, softmax over t.
__global__ __launch_bounds__(256) void k_attn_stats(const float* __restrict__ Qp, const float* __restrict__ Kp,
                                                    float* __restrict__ cmax, float* __restrict__ csum) {
  int bh = blockIdx.x; int b = bh >> 4, h = bh & 15;
  int s0 = blockIdx.y << 6;
  __shared__ float Ks[64][65];
  __shared__ float Qs[64][64];
  __shared__ float rm[4][64];
  __shared__ float rs[4][64];
  int tid = threadIdx.x;
  for (int i = tid; i < 4096; i += 256) {
    int r = i >> 6, c = i & 63;
    Ks[r][c] = Kp[(((size_t)b * TT + s0 + r) * HH + h) * DKK + c];
  }
  int sl = tid & 63, grp = tid >> 6;
  float m = -1e30f, sum = 0.f;
  for (int t0 = 0; t0 < TT; t0 += 64) {
    __syncthreads();
    for (int i = tid; i < 4096; i += 256) {
      int r = i >> 6, c = i & 63;
      Qs[r][c] = Qp[(((size_t)b * TT + t0 + r) * HH + h) * DKK + c];
    }
    __syncthreads();
    for (int tl = grp; tl < 64; tl += 4) {
      float dot = 0.f;
      #pragma unroll
      for (int c = 0; c < 64; ++c) dot += Qs[tl][c] * Ks[sl][c];
      dot *= 0.125f;
      float nm = fmaxf(m, dot);
      sum = sum * __expf(m - nm) + __expf(dot - nm);
      m = nm;
    }
  }
  rm[grp][sl] = m; rs[grp][sl] = sum;
  __syncthreads();
  if (grp == 0) {
    float M = m, S = sum;
    #pragma unroll
    for (int g = 1; g < 4; ++g) {
      float m2 = rm[g][sl], s2 = rs[g][sl];
      float nm = fmaxf(M, m2);
      S = S * __expf(M - nm) + s2 * __expf(m2 - nm);
      M = nm;
    }
    size_t o = (size_t)bh * TT + s0 + sl;
    cmax[o] = M; csum[o] = S;
  }
}

// ---------------- attention pass 2: O[t,v] = sum_s exp(score-cm[s])/cs[s] * V[s,v] ----------------
__global__ __launch_bounds__(256) void k_attn_apply(const float* __restrict__ Qp, const float* __restrict__ Kp,
                                                    const float* __restrict__ Vp,
                                                    const float* __restrict__ cmax, const float* __restrict__ csum,
                                                    float* __restrict__ Op) {
  int bh = blockIdx.x; int b = bh >> 4, h = bh & 15;
  int t0 = blockIdx.y << 6;
  __shared__ float Qs[64][64];
  __shared__ float KV[64][65];
  __shared__ float Ps[64][65];
  int tid = threadIdx.x;
  for (int i = tid; i < 4096; i += 256) {
    int r = i >> 6, c = i & 63;
    Qs[r][c] = Qp[(((size_t)b * TT + t0 + r) * HH + h) * DKK + c];
  }
  int low = tid & 63, grp = tid >> 6;
  float acc[16];
  #pragma unroll
  for (int j = 0; j < 16; ++j) acc[j] = 0.f;
  for (int s0 = 0; s0 < TT; s0 += 64) {
    __syncthreads();
    for (int i = tid; i < 4096; i += 256) {
      int r = i >> 6, c = i & 63;
      KV[r][c] = Kp[(((size_t)b * TT + s0 + r) * HH + h) * DKK + c];
    }
    __syncthreads();
    {
      float cm = cmax[(size_t)bh * TT + s0 + low];
      float ci = 1.f / csum[(size_t)bh * TT + s0 + low];
      for (int tl = grp; tl < 64; tl += 4) {
        float dot = 0.f;
        #pragma unroll
        for (int c = 0; c < 64; ++c) dot += Qs[tl][c] * KV[low][c];
        Ps[tl][low] = __expf(dot * 0.125f - cm) * ci;
      }
    }
    __syncthreads();
    for (int i = tid; i < 4096; i += 256) {
      int r = i >> 6, c = i & 63;
      KV[r][c] = Vp[(((size_t)b * TT + s0 + r) * HH + h) * DKK + c];
    }
    __syncthreads();
    #pragma unroll 4
    for (int ss = 0; ss < 64; ++ss) {
      float p = Ps[low][ss];
      #pragma unroll
      for (int j = 0; j < 16; ++j) acc[j] += p * KV[ss][(grp << 4) + j];
    }
  }
  #pragma unroll
  for (int j = 0; j < 16; ++j)
    Op[(((size_t)b * TT + t0 + low) * HH + h) * DKK + (grp << 4) + j] = acc[j];
}

// ---------------- O = norm(A + B) per row of 1024, unbiased std (ddof=1) ----------------
__global__ __launch_bounds__(256) void k_add_norm(const float* __restrict__ A, const float* __restrict__ Bv,
                                                  float* __restrict__ O) {
  int row = blockIdx.x, tid = threadIdx.x;
  const float* a = A + (size_t)row * DD;
  const float* b = Bv + (size_t)row * DD;
  __shared__ float red[256];
  float v[4]; float s = 0.f;
  #pragma unroll
  for (int i = 0; i < 4; ++i) { v[i] = a[tid + (i << 8)] + b[tid + (i << 8)]; s += v[i]; }
  red[tid] = s; __syncthreads();
  for (int t = 128; t > 0; t >>= 1) { if (tid < t) red[tid] += red[tid + t]; __syncthreads(); }
  float mean = red[0] * (1.f / 1024.f);
  __syncthreads();
  float vs = 0.f;
  #pragma unroll
  for (int i = 0; i < 4; ++i) { float d = v[i] - mean; vs += d * d; }
  red[tid] = vs; __syncthreads();
  for (int t = 128; t > 0; t >>= 1) { if (tid < t) red[tid] += red[tid + t]; __syncthreads(); }
  float inv = rsqrtf(red[0] * (1.f / 1023.f));
  #pragma unroll
  for (int i = 0; i < 4; ++i) O[(size_t)row * DD + tid + (i << 8)] = (v[i] - mean) * inv;
}

extern "C" void kernel_launch(void* const* d_in, const int* in_sizes, int n_in,
                              void* d_out, int out_size, void* d_ws, size_t ws_size,
                              hipStream_t stream) {
  (void)in_sizes; (void)n_in; (void)out_size; (void)ws_size;
  const float* x    = (const float*)d_in[0];
  const float* y    = (const float*)d_in[1];
  const float* Wq1  = (const float*)d_in[2];
  const float* Wk1  = (const float*)d_in[3];
  const float* Wv1  = (const float*)d_in[4];
  const float* Wo1  = (const float*)d_in[5];
  const float* Wq2  = (const float*)d_in[6];
  const float* Wk2  = (const float*)d_in[7];
  const float* Wv2  = (const float*)d_in[8];
  const float* Wo2  = (const float*)d_in[9];
  const float* w_in  = (const float*)d_in[10];
  const float* b_in  = (const float*)d_in[11];
  const float* w_out = (const float*)d_in[12];
  const float* b_out = (const float*)d_in[13];

  float* ws = (float*)d_ws;
  size_t off = 0;
  auto alloc = [&](size_t n) { float* p = ws + off; off += n; return p; };
  const size_t MR = (size_t)BB * TT;            // 4096 rows
  float* WtQ   = alloc((size_t)DD * HH * DKK);  // 1M floats each
  float* WtK   = alloc((size_t)DD * HH * DKK);
  float* WtV   = alloc((size_t)DD * HH * DKK);
  float* projQ = alloc(MR * DD);                // these four are contiguous:
  float* projK = alloc(MR * DD);                //   reused as ff1 (4096x4096)
  float* projV = alloc(MR * DD);
  float* mhaO  = alloc(MR * DD);
  float* out1  = alloc(MR * DD);
  float* out2  = alloc(MR * DD);
  float* ff2   = alloc(MR * DD);
  float* cmax  = alloc((size_t)BB * HH * TT);
  float* csum  = alloc((size_t)BB * HH * TT);
  float* ff1   = projQ;                         // 16M floats span

  dim3 blk(256);
  dim3 gW(HH * DKK);
  dim3 gR(4096);
  dim3 gGemmN(DD / 64, MR / 64);     // (16, 64)
  dim3 gGemmF(FFF / 64, MR / 64);    // (64, 64)
  dim3 gAttn(BB * HH, TT / 64);
  dim3 gNorm(MR);

  // output[0 : 4M] = x (pass-through)
  hipMemcpyAsync(d_out, (const void*)x, MR * DD * sizeof(float), hipMemcpyDeviceToDevice, stream);

  // ---- Layer 1: masked self-attention on y ----
  k_softmax_w<<<gW, blk, 0, stream>>>(Wq1, WtQ);
  k_softmax_w<<<gW, blk, 0, stream>>>(Wk1, WtK);
  k_reorder_w<<<gR, blk, 0, stream>>>(Wv1, WtV);
  k_gemm_nn<<<gGemmN, blk, 0, stream>>>(y, WtQ, projQ, 4096, 1024, 1024);
  k_gemm_nn<<<gGemmN, blk, 0, stream>>>(y, WtK, projK, 4096, 1024, 1024);
  k_gemm_nn<<<gGemmN, blk, 0, stream>>>(y, WtV, projV, 4096, 1024, 1024);
  k_attn_stats<<<gAttn, blk, 0, stream>>>(projQ, projK, cmax, csum);
  k_attn_apply<<<gAttn, blk, 0, stream>>>(projQ, projK, projV, cmax, csum, mhaO);
  k_gemm_nn<<<gGemmN, blk, 0, stream>>>(mhaO, Wo1, ff2, 4096, 1024, 1024);
  k_add_norm<<<gNorm, blk, 0, stream>>>(ff2, y, out1);

  // ---- Layer 2: cross-attention (Q from out1, K/V from x) ----
  k_reorder_w<<<gR, blk, 0, stream>>>(Wq2, WtQ);
  k_reorder_w<<<gR, blk, 0, stream>>>(Wk2, WtK);
  k_reorder_w<<<gR, blk, 0, stream>>>(Wv2, WtV);
  k_gemm_nn<<<gGemmN, blk, 0, stream>>>(out1, WtQ, projQ, 4096, 1024, 1024);
  k_gemm_nn<<<gGemmN, blk, 0, stream>>>(x, WtK, projK, 4096, 1024, 1024);
  k_gemm_nn<<<gGemmN, blk, 0, stream>>>(x, WtV, projV, 4096, 1024, 1024);
  k_attn_stats<<<gAttn, blk, 0, stream>>>(projQ, projK, cmax, csum);
  k_attn_apply<<<gAttn, blk, 0, stream>>>(projQ, projK, projV, cmax, csum, mhaO);
  k_gemm_nn<<<gGemmN, blk, 0, stream>>>(mhaO, Wo2, ff2, 4096, 1024, 1024);
  k_add_norm<<<gNorm, blk, 0, stream>>>(ff2, out1, out2);

  // ---- FF ----
  k_gemm_nt<<<gGemmF, blk, 0, stream>>>(out2, w_in, b_in, ff1, 4096, 4096, 1024, 1);
  k_gemm_nt<<<gGemmN, blk, 0, stream>>>(ff1, w_out, b_out, ff2, 4096, 1024, 4096, 0);
  k_add_norm<<<gNorm, blk, 0, stream>>>(ff2, out2, (float*)d_out + MR * DD);
}

// Round 2
// 1901.177 us; speedup vs baseline: 2.5855x; 2.5855x over previous
//
#include <hip/hip_runtime.h>
#include <hip/hip_bf16.h>

#define BB 4
#define TT 1024
#define DD 1024
#define HH 16
#define DKK 64
#define FFF 4096

typedef unsigned short u16;
typedef unsigned int u32;
typedef __attribute__((ext_vector_type(8))) short s16x8;
typedef __attribute__((ext_vector_type(4))) float f32x4;

static __device__ __forceinline__ float bf2f(u16 s) {
  union { u32 u; float f; } v; v.u = ((u32)s) << 16; return v.f;
}
static __device__ __forceinline__ u16 f2bf(float f) {
  union { float f; u32 u; } v; v.f = f;
  u32 r = v.u + 0x7FFFu + ((v.u >> 16) & 1u);
  return (u16)(r >> 16);
}

#define GLDS(gp, lp) __builtin_amdgcn_global_load_lds( \
    (const __attribute__((address_space(1))) u32*)(gp), \
    (__attribute__((address_space(3))) u32*)(lp), 16, 0, 0)

// ---------------- f32 -> bf16 elementwise ----------------
__global__ __launch_bounds__(256) void k_f2bf(const float* __restrict__ s, u16* __restrict__ d, int n) {
  int i = (blockIdx.x * 256 + threadIdx.x) * 4;
  if (i < n) {
    float4 v = *(const float4*)(s + i);
    u16 o[4] = { f2bf(v.x), f2bf(v.y), f2bf(v.z), f2bf(v.w) };
    *(ushort4*)(d + i) = *(ushort4*)o;
  }
}

// ---------------- masked softmax over d (axis -2), write bf16 B[n= h*64+k][d] ----------------
__global__ __launch_bounds__(256) void k_softmax_w_bf(const float* __restrict__ W, u16* __restrict__ Bt) {
  int col = blockIdx.x;           // h*64 + k
  int h = col >> 6, k = col & 63;
  int tid = threadIdx.x;
  const float* w = W + ((size_t)h * DD) * DKK + k;
  __shared__ float red[256];
  float m = -1e30f;
  for (int d = k + tid; d < DD; d += 256) m = fmaxf(m, w[(size_t)d * DKK]);
  red[tid] = m; __syncthreads();
  for (int s = 128; s > 0; s >>= 1) { if (tid < s) red[tid] = fmaxf(red[tid], red[tid + s]); __syncthreads(); }
  m = red[0]; __syncthreads();
  float sum = 0.f;
  for (int d = k + tid; d < DD; d += 256) sum += __expf(w[(size_t)d * DKK] - m);
  red[tid] = sum; __syncthreads();
  for (int s = 128; s > 0; s >>= 1) { if (tid < s) red[tid] += red[tid + s]; __syncthreads(); }
  float inv = 1.f / red[0];
  for (int d = tid; d < DD; d += 256) {
    float v = (d >= k) ? __expf(w[(size_t)d * DKK] - m) * inv : 0.f;
    Bt[(size_t)col * DD + d] = f2bf(v);
  }
}

// ---------------- reorder (H, D, DK) -> bf16 B[n=h*64+k][d] ----------------
__global__ __launch_bounds__(256) void k_reorder_w_bf(const float* __restrict__ W, u16* __restrict__ Bt) {
  int d0 = blockIdx.x << 6, h = blockIdx.y;
  __shared__ float t[64][65];
  int tid = threadIdx.x;
  const float* src = W + (size_t)h * DD * DKK + (size_t)d0 * DKK;
  #pragma unroll
  for (int i = 0; i < 16; ++i) {
    int e = i * 256 + tid; int r = e >> 6, c = e & 63;
    t[r][c] = src[(size_t)r * DKK + c];
  }
  __syncthreads();
  #pragma unroll
  for (int i = 0; i < 16; ++i) {
    int e = i * 256 + tid; int c = e >> 6, r = e & 63;
    Bt[((size_t)(h * 64 + c)) * DD + d0 + r] = f2bf(t[r][c]);
  }
}

// ---------------- transpose (K,N) f32 -> bf16 B[n][k] ----------------
__global__ __launch_bounds__(256) void k_transpose_bf(const float* __restrict__ W, u16* __restrict__ Bt) {
  int k0 = blockIdx.x << 6, n0 = blockIdx.y << 6;
  __shared__ float t[64][65];
  int tid = threadIdx.x;
  #pragma unroll
  for (int i = 0; i < 16; ++i) {
    int e = i * 256 + tid; int r = e >> 6, c = e & 63;
    t[r][c] = W[(size_t)(k0 + r) * DD + n0 + c];
  }
  __syncthreads();
  #pragma unroll
  for (int i = 0; i < 16; ++i) {
    int e = i * 256 + tid; int c = e >> 6, r = e & 63;
    Bt[(size_t)(n0 + c) * DD + k0 + r] = f2bf(t[r][c]);
  }
}

// ---------------- MFMA NT GEMM: C(MxN) = A(MxK) * B(NxK)^T  (bf16 in, f32 acc) ----------------
// BM=BN=128, BK=32, 256 threads (4 waves, 2x2), each wave 64x64 out.
__global__ __launch_bounds__(256) void k_mfma_nt(
    const u16* __restrict__ A, const u16* __restrict__ B,
    float* __restrict__ Cf, u16* __restrict__ Cb,
    const float* __restrict__ bias, int relu, int M, int N, int K) {
  __shared__ u16 As[128 * 32];
  __shared__ u16 Bs[128 * 32];
  int tid = threadIdx.x, wave = tid >> 6, lane = tid & 63;
  int row0 = blockIdx.y << 7, col0 = blockIdx.x << 7;
  int wm = (wave >> 1) << 6, wn = (wave & 1) << 6;

  f32x4 acc[4][4];
  #pragma unroll
  for (int m = 0; m < 4; ++m)
    #pragma unroll
    for (int n = 0; n < 4; ++n) acc[m][n] = f32x4{0.f, 0.f, 0.f, 0.f};

  // staging geometry: tile [128][32] bf16 = 8192 B = 8 chunks of 1024 B (16 rows each)
  int c0 = wave * 2, c1 = wave * 2 + 1;
  int r0 = (c0 << 4) + (lane >> 2);
  int r1 = (c1 << 4) + (lane >> 2);
  int ce = (lane & 3) << 3;
  const u16* Ag0 = A + (size_t)(row0 + r0) * K + ce;
  const u16* Ag1 = A + (size_t)(row0 + r1) * K + ce;
  const u16* Bg0 = B + (size_t)(col0 + r0) * K + ce;
  const u16* Bg1 = B + (size_t)(col0 + r1) * K + ce;
  u16* Al0 = As + c0 * 512;  u16* Al1 = As + c1 * 512;
  u16* Bl0 = Bs + c0 * 512;  u16* Bl1 = Bs + c1 * 512;

  int fr = lane & 15, kg = (lane >> 4) << 3;
  const u16* ArdBase = As + (size_t)(wm + fr) * 32 + kg;
  const u16* BrdBase = Bs + (size_t)(wn + fr) * 32 + kg;

  for (int k0 = 0; k0 < K; k0 += 32) {
    GLDS(Ag0 + k0, Al0);
    GLDS(Ag1 + k0, Al1);
    GLDS(Bg0 + k0, Bl0);
    GLDS(Bg1 + k0, Bl1);
    __syncthreads();          // drains vmcnt(0) then barrier
    s16x8 aF[4], bF[4];
    #pragma unroll
    for (int m = 0; m < 4; ++m) aF[m] = *(const s16x8*)(ArdBase + m * 16 * 32);
    #pragma unroll
    for (int n = 0; n < 4; ++n) bF[n] = *(const s16x8*)(BrdBase + n * 16 * 32);
    #pragma unroll
    for (int m = 0; m < 4; ++m)
      #pragma unroll
      for (int n = 0; n < 4; ++n)
        acc[m][n] = __builtin_amdgcn_mfma_f32_16x16x32_bf16(aF[m], bF[n], acc[m][n], 0, 0, 0);
    __syncthreads();          // protect LDS before next stage
  }

  int fq = (lane >> 4) << 2;
  #pragma unroll
  for (int n = 0; n < 4; ++n) {
    int col = col0 + wn + n * 16 + fr;
    float bs = bias ? bias[col] : 0.f;
    #pragma unroll
    for (int m = 0; m < 4; ++m) {
      #pragma unroll
      for (int r = 0; r < 4; ++r) {
        int row = row0 + wm + m * 16 + fq + r;
        float v = acc[m][n][r] + bs;
        if (relu) v = fmaxf(v, 0.f);
        size_t o = (size_t)row * N + col;
        if (Cf) Cf[o] = v;
        if (Cb) Cb[o] = f2bf(v);
      }
    }
  }
}

// ---------------- stage 64x64 bf16 tile (global row stride 1024) -> f32 LDS ----------------
template<int PITCH>
static __device__ __forceinline__ void stage64(const u16* __restrict__ g, float (*S)[PITCH], int tid) {
  #pragma unroll
  for (int i = 0; i < 2; ++i) {
    int e = ((i << 8) + tid) << 3;
    int r = e >> 6, c = e & 63;
    uint4 v = *(const uint4*)(g + (size_t)r * 1024 + c);
    S[r][c + 0] = bf2f((u16)(v.x & 0xffff)); S[r][c + 1] = bf2f((u16)(v.x >> 16));
    S[r][c + 2] = bf2f((u16)(v.y & 0xffff)); S[r][c + 3] = bf2f((u16)(v.y >> 16));
    S[r][c + 4] = bf2f((u16)(v.z & 0xffff)); S[r][c + 5] = bf2f((u16)(v.z >> 16));
    S[r][c + 6] = bf2f((u16)(v.w & 0xffff)); S[r][c + 7] = bf2f((u16)(v.w >> 16));
  }
}

// ---------------- attention pass 1: per-column (over t) max & sum of exp ----------------
__global__ __launch_bounds__(256) void k_attn_stats(const u16* __restrict__ Qp, const u16* __restrict__ Kp,
                                                    float* __restrict__ cmax, float* __restrict__ csum) {
  int bh = blockIdx.x; int b = bh >> 4, h = bh & 15;
  int s0 = blockIdx.y << 6;
  __shared__ float Ks[64][65];
  __shared__ float Qs[64][64];
  __shared__ float rm[4][64];
  __shared__ float rs[4][64];
  int tid = threadIdx.x;
  stage64(Kp + (((size_t)b * TT + s0) * HH + h) * DKK, Ks, tid);
  int sl = tid & 63, grp = tid >> 6;
  float m = -1e30f, sum = 0.f;
  for (int t0 = 0; t0 < TT; t0 += 64) {
    __syncthreads();
    stage64(Qp + (((size_t)b * TT + t0) * HH + h) * DKK, Qs, tid);
    __syncthreads();
    for (int tl = grp; tl < 64; tl += 4) {
      float dot = 0.f;
      #pragma unroll
      for (int c = 0; c < 64; ++c) dot += Qs[tl][c] * Ks[sl][c];
      dot *= 0.125f;
      float nm = fmaxf(m, dot);
      sum = sum * __expf(m - nm) + __expf(dot - nm);
      m = nm;
    }
  }
  rm[grp][sl] = m; rs[grp][sl] = sum;
  __syncthreads();
  if (grp == 0) {
    float M = m, S = sum;
    #pragma unroll
    for (int g = 1; g < 4; ++g) {
      float m2 = rm[g][sl], s2 = rs[g][sl];
      float nm = fmaxf(M, m2);
      S = S * __expf(M - nm) + s2 * __expf(m2 - nm);
      M = nm;
    }
    size_t o = (size_t)bh * TT + s0 + sl;
    cmax[o] = M; csum[o] = S;
  }
}

// ---------------- attention pass 2: O[t,v] = sum_s exp(score-cm[s])/cs[s] * V[s,v] ----------------
__global__ __launch_bounds__(256) void k_attn_apply(const u16* __restrict__ Qp, const u16* __restrict__ Kp,
                                                    const u16* __restrict__ Vp,
                                                    const float* __restrict__ cmax, const float* __restrict__ csum,
                                                    u16* __restrict__ Op) {
  int bh = blockIdx.x; int b = bh >> 4, h = bh & 15;
  int t0 = blockIdx.y << 6;
  __shared__ float Qs[64][64];
  __shared__ float KV[64][65];
  __shared__ float Ps[64][65];
  int tid = threadIdx.x;
  stage64(Qp + (((size_t)b * TT + t0) * HH + h) * DKK, Qs, tid);
  int low = tid & 63, grp = tid >> 6;
  float acc[16];
  #pragma unroll
  for (int j = 0; j < 16; ++j) acc[j] = 0.f;
  for (int s0 = 0; s0 < TT; s0 += 64) {
    __syncthreads();
    stage64(Kp + (((size_t)b * TT + s0) * HH + h) * DKK, KV, tid);
    __syncthreads();
    {
      float cm = cmax[(size_t)bh * TT + s0 + low];
      float ci = 1.f / csum[(size_t)bh * TT + s0 + low];
      for (int tl = grp; tl < 64; tl += 4) {
        float dot = 0.f;
        #pragma unroll
        for (int c = 0; c < 64; ++c) dot += Qs[tl][c] * KV[low][c];
        Ps[tl][low] = __expf(dot * 0.125f - cm) * ci;
      }
    }
    __syncthreads();
    stage64(Vp + (((size_t)b * TT + s0) * HH + h) * DKK, KV, tid);
    __syncthreads();
    #pragma unroll 4
    for (int ss = 0; ss < 64; ++ss) {
      float p = Ps[low][ss];
      #pragma unroll
      for (int j = 0; j < 16; ++j) acc[j] += p * KV[ss][(grp << 4) + j];
    }
  }
  u16 ob[16];
  #pragma unroll
  for (int j = 0; j < 16; ++j) ob[j] = f2bf(acc[j]);
  u16* dst = Op + (((size_t)b * TT + t0 + low) * HH + h) * DKK + (grp << 4);
  ((uint4*)dst)[0] = ((uint4*)ob)[0];
  ((uint4*)dst)[1] = ((uint4*)ob)[1];
}

// ---------------- O = norm(A + Bv) per row of 1024; optional bf16 copy ----------------
__global__ __launch_bounds__(256) void k_add_norm(const float* __restrict__ A, const float* __restrict__ Bv,
                                                  float* __restrict__ O, u16* __restrict__ Ob) {
  int row = blockIdx.x, tid = threadIdx.x;
  const float* a = A + (size_t)row * DD;
  const float* b = Bv + (size_t)row * DD;
  __shared__ float red[256];
  float v[4]; float s = 0.f;
  #pragma unroll
  for (int i = 0; i < 4; ++i) { v[i] = a[tid + (i << 8)] + b[tid + (i << 8)]; s += v[i]; }
  red[tid] = s; __syncthreads();
  for (int t = 128; t > 0; t >>= 1) { if (tid < t) red[tid] += red[tid + t]; __syncthreads(); }
  float mean = red[0] * (1.f / 1024.f);
  __syncthreads();
  float vs = 0.f;
  #pragma unroll
  for (int i = 0; i < 4; ++i) { float d = v[i] - mean; vs += d * d; }
  red[tid] = vs; __syncthreads();
  for (int t = 128; t > 0; t >>= 1) { if (tid < t) red[tid] += red[tid + t]; __syncthreads(); }
  float inv = rsqrtf(red[0] * (1.f / 1023.f));
  #pragma unroll
  for (int i = 0; i < 4; ++i) {
    float o = (v[i] - mean) * inv;
    O[(size_t)row * DD + tid + (i << 8)] = o;
    if (Ob) Ob[(size_t)row * DD + tid + (i << 8)] = f2bf(o);
  }
}

extern "C" void kernel_launch(void* const* d_in, const int* in_sizes, int n_in,
                              void* d_out, int out_size, void* d_ws, size_t ws_size,
                              hipStream_t stream) {
  (void)in_sizes; (void)n_in; (void)out_size; (void)ws_size;
  const float* x    = (const float*)d_in[0];
  const float* y    = (const float*)d_in[1];
  const float* Wq1  = (const float*)d_in[2];
  const float* Wk1  = (const float*)d_in[3];
  const float* Wv1  = (const float*)d_in[4];
  const float* Wo1  = (const float*)d_in[5];
  const float* Wq2  = (const float*)d_in[6];
  const float* Wk2  = (const float*)d_in[7];
  const float* Wv2  = (const float*)d_in[8];
  const float* Wo2  = (const float*)d_in[9];
  const float* w_in  = (const float*)d_in[10];
  const float* b_in  = (const float*)d_in[11];
  const float* w_out = (const float*)d_in[12];
  const float* b_out = (const float*)d_in[13];

  float* ws = (float*)d_ws;
  size_t off = 0;
  auto allocw = [&](size_t nw) { float* p = ws + off; off += nw; return p; };
  const size_t MR = (size_t)BB * TT;           // 4096
  const size_t ND = MR * DD;                   // 4.19M elems

  u16* Bq   = (u16*)allocw(512 * 1024);        // 1024x1024 bf16 (N,K)
  u16* Bk   = (u16*)allocw(512 * 1024);
  u16* Bv   = (u16*)allocw(512 * 1024);
  u16* Bwo  = (u16*)allocw(512 * 1024);
  u16* Wi   = (u16*)allocw(2 * 1024 * 1024);   // w_in bf16 (4096,1024)
  u16* Wob  = (u16*)allocw(2 * 1024 * 1024);   // w_out bf16 (1024,4096)
  u16* xbf  = (u16*)allocw(ND / 2);
  u16* ybf  = (u16*)allocw(ND / 2);            // later reused as out2_bf
  u16* REG  = (u16*)allocw(ND * 2);            // Qb|Kb|Vb|Mb, or ff1 (4096x4096 bf16)
  float* ff2  = allocw(ND);
  float* out1 = allocw(ND);
  float* out2 = allocw(ND);
  float* cmax = allocw((size_t)BB * HH * TT);
  float* csum = allocw((size_t)BB * HH * TT);

  u16* Qb = REG;
  u16* Kb = REG + ND;
  u16* Vb = REG + 2 * ND;
  u16* Mb = REG + 3 * ND;   // mhaO; also hosts out1_bf between layers
  u16* ff1b = REG;          // 16.7M bf16 spans all four slots
  u16* out2bf = ybf;        // ybf dead after layer-1 projections

  dim3 blk(256);
  dim3 gConv(4096);
  dim3 gSm(1024);
  dim3 gRw(16, 16);
  dim3 gP(8, 32);           // N=1024 tiles x M=4096 tiles
  dim3 gF1(32, 32);         // N=4096
  dim3 gAttn(BB * HH, TT / 64);
  dim3 gNorm(MR);

  // output[0 : ND] = x (pass-through)
  hipMemcpyAsync(d_out, (const void*)x, ND * sizeof(float), hipMemcpyDeviceToDevice, stream);

  // conversions
  k_f2bf<<<gConv, blk, 0, stream>>>(y, ybf, (int)ND);
  k_f2bf<<<gConv, blk, 0, stream>>>(x, xbf, (int)ND);
  k_f2bf<<<gConv, blk, 0, stream>>>(w_in, Wi, FFF * DD);
  k_f2bf<<<gConv, blk, 0, stream>>>(w_out, Wob, DD * FFF);

  // ---- Layer 1: masked self-attention on y ----
  k_softmax_w_bf<<<gSm, blk, 0, stream>>>(Wq1, Bq);
  k_softmax_w_bf<<<gSm, blk, 0, stream>>>(Wk1, Bk);
  k_reorder_w_bf<<<gRw, blk, 0, stream>>>(Wv1, Bv);
  k_transpose_bf<<<gRw, blk, 0, stream>>>(Wo1, Bwo);
  k_mfma_nt<<<gP, blk, 0, stream>>>(ybf, Bq, nullptr, Qb, nullptr, 0, 4096, 1024, 1024);
  k_mfma_nt<<<gP, blk, 0, stream>>>(ybf, Bk, nullptr, Kb, nullptr, 0, 4096, 1024, 1024);
  k_mfma_nt<<<gP, blk, 0, stream>>>(ybf, Bv, nullptr, Vb, nullptr, 0, 4096, 1024, 1024);
  k_attn_stats<<<gAttn, blk, 0, stream>>>(Qb, Kb, cmax, csum);
  k_attn_apply<<<gAttn, blk, 0, stream>>>(Qb, Kb, Vb, cmax, csum, Mb);
  k_mfma_nt<<<gP, blk, 0, stream>>>(Mb, Bwo, ff2, nullptr, nullptr, 0, 4096, 1024, 1024);
  k_add_norm<<<gNorm, blk, 0, stream>>>(ff2, y, out1, Mb /* out1_bf */);

  // ---- Layer 2: cross-attention (Q from out1, K/V from x) ----
  k_reorder_w_bf<<<gRw, blk, 0, stream>>>(Wq2, Bq);
  k_reorder_w_bf<<<gRw, blk, 0, stream>>>(Wk2, Bk);
  k_reorder_w_bf<<<gRw, blk, 0, stream>>>(Wv2, Bv);
  k_transpose_bf<<<gRw, blk, 0, stream>>>(Wo2, Bwo);
  k_mfma_nt<<<gP, blk, 0, stream>>>(Mb /* out1_bf */, Bq, nullptr, Qb, nullptr, 0, 4096, 1024, 1024);
  k_mfma_nt<<<gP, blk, 0, stream>>>(xbf, Bk, nullptr, Kb, nullptr, 0, 4096, 1024, 1024);
  k_mfma_nt<<<gP, blk, 0, stream>>>(xbf, Bv, nullptr, Vb, nullptr, 0, 4096, 1024, 1024);
  k_attn_stats<<<gAttn, blk, 0, stream>>>(Qb, Kb, cmax, csum);
  k_attn_apply<<<gAttn, blk, 0, stream>>>(Qb, Kb, Vb, cmax, csum, Mb);
  k_mfma_nt<<<gP, blk, 0, stream>>>(Mb, Bwo, ff2, nullptr, nullptr, 0, 4096, 1024, 1024);
  k_add_norm<<<gNorm, blk, 0, stream>>>(ff2, out1, out2, out2bf);

  // ---- FF ----
  k_mfma_nt<<<gF1, blk, 0, stream>>>(out2bf, Wi, nullptr, ff1b, b_in, 1, 4096, 4096, 1024);
  k_mfma_nt<<<gP, blk, 0, stream>>>(ff1b, Wob, ff2, nullptr, b_out, 0, 4096, 1024, 4096);
  k_add_norm<<<gNorm, blk, 0, stream>>>(ff2, out2, (float*)d_out + ND, nullptr);
}

// Round 3
// 609.743 us; speedup vs baseline: 8.0615x; 3.1180x over previous
//
#include <hip/hip_runtime.h>
#include <hip/hip_bf16.h>

#define BB 4
#define TT 1024
#define DD 1024
#define HH 16
#define DKK 64
#define FFF 4096

typedef unsigned short u16;
typedef unsigned int u32;
typedef __attribute__((ext_vector_type(8))) short s16x8;
typedef __attribute__((ext_vector_type(4))) float f32x4;

static __device__ __forceinline__ float bf2f(u16 s) {
  union { u32 u; float f; } v; v.u = ((u32)s) << 16; return v.f;
}
static __device__ __forceinline__ u16 f2bf(float f) {
  union { float f; u32 u; } v; v.f = f;
  u32 r = v.u + 0x7FFFu + ((v.u >> 16) & 1u);
  return (u16)(r >> 16);
}

#define GLDS(gp, lp) __builtin_amdgcn_global_load_lds( \
    (const __attribute__((address_space(1))) u32*)(gp), \
    (__attribute__((address_space(3))) u32*)(lp), 16, 0, 0)

// ---------------- f32 -> bf16 elementwise ----------------
__global__ __launch_bounds__(256) void k_f2bf(const float* __restrict__ s, u16* __restrict__ d, int n) {
  int i = (blockIdx.x * 256 + threadIdx.x) * 4;
  if (i < n) {
    float4 v = *(const float4*)(s + i);
    u16 o[4] = { f2bf(v.x), f2bf(v.y), f2bf(v.z), f2bf(v.w) };
    *(ushort4*)(d + i) = *(ushort4*)o;
  }
}

// ---------------- masked softmax over d (axis -2), write bf16 B[n= h*64+k][d] ----------------
__global__ __launch_bounds__(256) void k_softmax_w_bf(const float* __restrict__ W, u16* __restrict__ Bt) {
  int col = blockIdx.x;           // h*64 + k
  int h = col >> 6, k = col & 63;
  int tid = threadIdx.x;
  const float* w = W + ((size_t)h * DD) * DKK + k;
  __shared__ float red[256];
  float m = -1e30f;
  for (int d = k + tid; d < DD; d += 256) m = fmaxf(m, w[(size_t)d * DKK]);
  red[tid] = m; __syncthreads();
  for (int s = 128; s > 0; s >>= 1) { if (tid < s) red[tid] = fmaxf(red[tid], red[tid + s]); __syncthreads(); }
  m = red[0]; __syncthreads();
  float sum = 0.f;
  for (int d = k + tid; d < DD; d += 256) sum += __expf(w[(size_t)d * DKK] - m);
  red[tid] = sum; __syncthreads();
  for (int s = 128; s > 0; s >>= 1) { if (tid < s) red[tid] += red[tid + s]; __syncthreads(); }
  float inv = 1.f / red[0];
  for (int d = tid; d < DD; d += 256) {
    float v = (d >= k) ? __expf(w[(size_t)d * DKK] - m) * inv : 0.f;
    Bt[(size_t)col * DD + d] = f2bf(v);
  }
}

// ---------------- reorder (H, D, DK) -> bf16 B[n=h*64+k][d] ----------------
__global__ __launch_bounds__(256) void k_reorder_w_bf(const float* __restrict__ W, u16* __restrict__ Bt) {
  int d0 = blockIdx.x << 6, h = blockIdx.y;
  __shared__ float t[64][65];
  int tid = threadIdx.x;
  const float* src = W + (size_t)h * DD * DKK + (size_t)d0 * DKK;
  #pragma unroll
  for (int i = 0; i < 16; ++i) {
    int e = i * 256 + tid; int r = e >> 6, c = e & 63;
    t[r][c] = src[(size_t)r * DKK + c];
  }
  __syncthreads();
  #pragma unroll
  for (int i = 0; i < 16; ++i) {
    int e = i * 256 + tid; int c = e >> 6, r = e & 63;
    Bt[((size_t)(h * 64 + c)) * DD + d0 + r] = f2bf(t[r][c]);
  }
}

// ---------------- transpose (K,N) f32 -> bf16 B[n][k] ----------------
__global__ __launch_bounds__(256) void k_transpose_bf(const float* __restrict__ W, u16* __restrict__ Bt) {
  int k0 = blockIdx.x << 6, n0 = blockIdx.y << 6;
  __shared__ float t[64][65];
  int tid = threadIdx.x;
  #pragma unroll
  for (int i = 0; i < 16; ++i) {
    int e = i * 256 + tid; int r = e >> 6, c = e & 63;
    t[r][c] = W[(size_t)(k0 + r) * DD + n0 + c];
  }
  __syncthreads();
  #pragma unroll
  for (int i = 0; i < 16; ++i) {
    int e = i * 256 + tid; int c = e >> 6, r = e & 63;
    Bt[(size_t)(n0 + c) * DD + k0 + r] = f2bf(t[r][c]);
  }
}

// ---------------- MFMA NT GEMM: C(MxN) = A(MxK) * B(NxK)^T  (bf16 in, f32 acc) ----------------
// Outputs: Cf (f32 row-major), Cb (bf16 row-major), Ct (bf16 col-major, pitch M)
__global__ __launch_bounds__(256) void k_mfma_nt(
    const u16* __restrict__ A, const u16* __restrict__ B,
    float* __restrict__ Cf, u16* __restrict__ Cb, u16* __restrict__ Ct,
    const float* __restrict__ bias, int relu, int M, int N, int K) {
  __shared__ u16 As[128 * 32];
  __shared__ u16 Bs[128 * 32];
  int tid = threadIdx.x, wave = tid >> 6, lane = tid & 63;
  int row0 = blockIdx.y << 7, col0 = blockIdx.x << 7;
  int wm = (wave >> 1) << 6, wn = (wave & 1) << 6;

  f32x4 acc[4][4];
  #pragma unroll
  for (int m = 0; m < 4; ++m)
    #pragma unroll
    for (int n = 0; n < 4; ++n) acc[m][n] = f32x4{0.f, 0.f, 0.f, 0.f};

  int c0 = wave * 2, c1 = wave * 2 + 1;
  int r0 = (c0 << 4) + (lane >> 2);
  int r1 = (c1 << 4) + (lane >> 2);
  int ce = (lane & 3) << 3;
  const u16* Ag0 = A + (size_t)(row0 + r0) * K + ce;
  const u16* Ag1 = A + (size_t)(row0 + r1) * K + ce;
  const u16* Bg0 = B + (size_t)(col0 + r0) * K + ce;
  const u16* Bg1 = B + (size_t)(col0 + r1) * K + ce;
  u16* Al0 = As + c0 * 512;  u16* Al1 = As + c1 * 512;
  u16* Bl0 = Bs + c0 * 512;  u16* Bl1 = Bs + c1 * 512;

  int fr = lane & 15, kg = (lane >> 4) << 3;
  const u16* ArdBase = As + (size_t)(wm + fr) * 32 + kg;
  const u16* BrdBase = Bs + (size_t)(wn + fr) * 32 + kg;

  for (int k0 = 0; k0 < K; k0 += 32) {
    GLDS(Ag0 + k0, Al0);
    GLDS(Ag1 + k0, Al1);
    GLDS(Bg0 + k0, Bl0);
    GLDS(Bg1 + k0, Bl1);
    __syncthreads();
    s16x8 aF[4], bF[4];
    #pragma unroll
    for (int m = 0; m < 4; ++m) aF[m] = *(const s16x8*)(ArdBase + m * 16 * 32);
    #pragma unroll
    for (int n = 0; n < 4; ++n) bF[n] = *(const s16x8*)(BrdBase + n * 16 * 32);
    #pragma unroll
    for (int m = 0; m < 4; ++m)
      #pragma unroll
      for (int n = 0; n < 4; ++n)
        acc[m][n] = __builtin_amdgcn_mfma_f32_16x16x32_bf16(aF[m], bF[n], acc[m][n], 0, 0, 0);
    __syncthreads();
  }

  int fq = (lane >> 4) << 2;
  #pragma unroll
  for (int n = 0; n < 4; ++n) {
    int col = col0 + wn + n * 16 + fr;
    float bs = bias ? bias[col] : 0.f;
    #pragma unroll
    for (int m = 0; m < 4; ++m) {
      float v[4];
      #pragma unroll
      for (int r = 0; r < 4; ++r) {
        v[r] = acc[m][n][r] + bs;
        if (relu) v[r] = fmaxf(v[r], 0.f);
      }
      int rowb = row0 + wm + m * 16 + fq;
      if (Cf) {
        #pragma unroll
        for (int r = 0; r < 4; ++r) Cf[(size_t)(rowb + r) * N + col] = v[r];
      }
      if (Cb) {
        #pragma unroll
        for (int r = 0; r < 4; ++r) Cb[(size_t)(rowb + r) * N + col] = f2bf(v[r]);
      }
      if (Ct) {
        u16 pb[4] = { f2bf(v[0]), f2bf(v[1]), f2bf(v[2]), f2bf(v[3]) };
        uint2 w; w.x = (u32)pb[0] | ((u32)pb[1] << 16); w.y = (u32)pb[2] | ((u32)pb[3] << 16);
        *(uint2*)(Ct + (size_t)col * M + rowb) = w;
      }
    }
  }
}

// ---------------- stage 64x64 bf16 (global pitch gp) -> padded LDS [64][72] ----------------
static __device__ __forceinline__ void stage_pad(const u16* __restrict__ g, int gp, u16* L, int tid) {
  #pragma unroll
  for (int i = 0; i < 2; ++i) {
    int c = (i << 8) + tid;                 // 0..511 chunks of 8
    int row = c >> 3, col8 = (c & 7) << 3;
    uint4 v = *(const uint4*)(g + (size_t)row * gp + col8);
    *(uint4*)(L + row * 72 + col8) = v;
  }
}

// ---------------- attention pass 1 (MFMA): per-(bh,s) max & sum over t ----------------
// S[t][s] = dot(Q[t],K[s])/8 ; softmax over t. mfma(Q,K): lane holds s=lane&15, 16 t vals.
__global__ __launch_bounds__(256) void k_attn_stats_mfma(const u16* __restrict__ Qb, const u16* __restrict__ Kb,
                                                         float* __restrict__ cmax, float* __restrict__ csum) {
  __shared__ u16 Ks[64 * 72];
  __shared__ u16 Qs[64 * 72];
  int tid = threadIdx.x, wave = tid >> 6, lane = tid & 63;
  int bh = blockIdx.x, b = bh >> 4, h = bh & 15;
  int s0 = blockIdx.y << 6;
  stage_pad(Kb + ((size_t)(b * TT + s0)) * DD + h * 64, DD, Ks, tid);
  __syncthreads();
  int fr = lane & 15, g = lane >> 4;
  const u16* Bbase = Ks + (wave * 16 + fr) * 72 + g * 8;   // B-frag: K rows (n = s)
  const u16* Abase = Qs + fr * 72 + g * 8;                 // A-frag: Q rows (m = t)
  s16x8 bF0 = *(const s16x8*)(Bbase);
  s16x8 bF1 = *(const s16x8*)(Bbase + 32);
  float m = -1e30f, sum = 0.f;
  for (int t0 = 0; t0 < TT; t0 += 64) {
    __syncthreads();
    stage_pad(Qb + ((size_t)(b * TT + t0)) * DD + h * 64, DD, Qs, tid);
    __syncthreads();
    #pragma unroll
    for (int mt = 0; mt < 4; ++mt) {
      f32x4 acc = f32x4{0.f, 0.f, 0.f, 0.f};
      s16x8 a0 = *(const s16x8*)(Abase + mt * 16 * 72);
      s16x8 a1 = *(const s16x8*)(Abase + mt * 16 * 72 + 32);
      acc = __builtin_amdgcn_mfma_f32_16x16x32_bf16(a0, bF0, acc, 0, 0, 0);
      acc = __builtin_amdgcn_mfma_f32_16x16x32_bf16(a1, bF1, acc, 0, 0, 0);
      float v0 = acc[0] * 0.125f, v1 = acc[1] * 0.125f, v2 = acc[2] * 0.125f, v3 = acc[3] * 0.125f;
      float tm = fmaxf(fmaxf(v0, v1), fmaxf(v2, v3));
      float nm = fmaxf(m, tm);
      sum = sum * __expf(m - nm) + __expf(v0 - nm) + __expf(v1 - nm) + __expf(v2 - nm) + __expf(v3 - nm);
      m = nm;
    }
  }
  // combine the 4 lane-groups holding the same s (xor 16, 32)
  #pragma unroll
  for (int mask = 16; mask <= 32; mask <<= 1) {
    float m2 = __shfl_xor(m, mask, 64);
    float s2 = __shfl_xor(sum, mask, 64);
    float nm = fmaxf(m, m2);
    sum = sum * __expf(m - nm) + s2 * __expf(m2 - nm);
    m = nm;
  }
  if (lane < 16) {
    size_t o = (size_t)bh * TT + s0 + wave * 16 + lane;
    cmax[o] = m; csum[o] = sum;
  }
}

// ---------------- attention pass 2 (MFMA): O[t][v] = sum_s exp(S-cm[s])/cs[s] * V[s][v] ----------------
// S^T via mfma(K,Q): lane holds t=lane&15 fixed, s spans tiles. P staged in swizzled LDS,
// PV via mfma(P, V^T) with V pre-transposed in global (col-major, pitch 4096).
__global__ __launch_bounds__(256) void k_attn_apply_mfma(const u16* __restrict__ Qb, const u16* __restrict__ Kb,
                                                         const u16* __restrict__ Vt,
                                                         const float* __restrict__ cmax, const float* __restrict__ csum,
                                                         u16* __restrict__ Op) {
  __shared__ u16 Qs[64 * 72];
  __shared__ u16 Ks[64 * 72];
  __shared__ u16 VTs[64 * 72];
  __shared__ u16 Pl[4 * 1024];     // per-wave [16 t][64 s] bf16, XOR-swizzled
  __shared__ float cmL[64];
  __shared__ float rcsL[64];
  int tid = threadIdx.x, wave = tid >> 6, lane = tid & 63;
  int bh = blockIdx.x, b = bh >> 4, h = bh & 15;
  int t0 = blockIdx.y << 6;
  stage_pad(Qb + ((size_t)(b * TT + t0)) * DD + h * 64, DD, Qs, tid);
  __syncthreads();
  int fr = lane & 15, g = lane >> 4;
  const u16* QbF = Qs + (wave * 16 + fr) * 72 + g * 8;   // B-frag (n = t)
  const u16* KaF = Ks + fr * 72 + g * 8;                 // A-frag rows s
  char* Pw = (char*)(Pl + wave * 1024);
  uint swz = ((uint)(lane & 7)) << 4;
  s16x8 qF0 = *(const s16x8*)(QbF);
  s16x8 qF1 = *(const s16x8*)(QbF + 32);
  f32x4 acc_o[4];
  #pragma unroll
  for (int nt = 0; nt < 4; ++nt) acc_o[nt] = f32x4{0.f, 0.f, 0.f, 0.f};
  const size_t cbase = (size_t)bh * TT;

  for (int s0 = 0; s0 < TT; s0 += 64) {
    __syncthreads();
    stage_pad(Kb + ((size_t)(b * TT + s0)) * DD + h * 64, DD, Ks, tid);
    stage_pad(Vt + (size_t)(h * 64) * 4096 + (size_t)b * TT + s0, 4096, VTs, tid);
    if (tid < 64) cmL[tid] = cmax[cbase + s0 + tid];
    else if (tid < 128) rcsL[tid - 64] = 1.f / csum[cbase + s0 + tid - 64];
    __syncthreads();
    // S^T tiles + exp -> P
    #pragma unroll
    for (int mt = 0; mt < 4; ++mt) {
      f32x4 acc = f32x4{0.f, 0.f, 0.f, 0.f};
      s16x8 a0 = *(const s16x8*)(KaF + mt * 16 * 72);
      s16x8 a1 = *(const s16x8*)(KaF + mt * 16 * 72 + 32);
      acc = __builtin_amdgcn_mfma_f32_16x16x32_bf16(a0, qF0, acc, 0, 0, 0);
      acc = __builtin_amdgcn_mfma_f32_16x16x32_bf16(a1, qF1, acc, 0, 0, 0);
      f32x4 cm4 = *(const f32x4*)&cmL[mt * 16 + g * 4];
      f32x4 rc4 = *(const f32x4*)&rcsL[mt * 16 + g * 4];
      u16 pb[4];
      #pragma unroll
      for (int r = 0; r < 4; ++r)
        pb[r] = f2bf(__expf(acc[r] * 0.125f - cm4[r]) * rc4[r]);
      uint woff = (uint)fr * 128 + (uint)(mt * 16 + g * 4) * 2;
      uint2 wv; wv.x = (u32)pb[0] | ((u32)pb[1] << 16); wv.y = (u32)pb[2] | ((u32)pb[3] << 16);
      *(uint2*)(Pw + (woff ^ swz)) = wv;
    }
    // PV: A = P (own wave's tile), B = V^T
    uint rbase = (uint)fr * 128;
    s16x8 pF0 = *(const s16x8*)(Pw + ((rbase + g * 16) ^ swz));
    s16x8 pF1 = *(const s16x8*)(Pw + ((rbase + 64 + g * 16) ^ swz));
    #pragma unroll
    for (int nt = 0; nt < 4; ++nt) {
      s16x8 v0 = *(const s16x8*)(VTs + (nt * 16 + fr) * 72 + g * 8);
      s16x8 v1 = *(const s16x8*)(VTs + (nt * 16 + fr) * 72 + 32 + g * 8);
      acc_o[nt] = __builtin_amdgcn_mfma_f32_16x16x32_bf16(pF0, v0, acc_o[nt], 0, 0, 0);
      acc_o[nt] = __builtin_amdgcn_mfma_f32_16x16x32_bf16(pF1, v1, acc_o[nt], 0, 0, 0);
    }
  }
  // epilogue: O rows t = t0 + wave*16 + g*4 + r, cols v = nt*16 + fr
  int tg = t0 + wave * 16 + g * 4;
  #pragma unroll
  for (int nt = 0; nt < 4; ++nt) {
    #pragma unroll
    for (int r = 0; r < 4; ++r) {
      Op[((size_t)(b * TT + tg + r)) * DD + h * 64 + nt * 16 + fr] = f2bf(acc_o[nt][r]);
    }
  }
}

// ---------------- O = norm(A + Bv) per row of 1024; optional bf16 copy ----------------
__global__ __launch_bounds__(256) void k_add_norm(const float* __restrict__ A, const float* __restrict__ Bv,
                                                  float* __restrict__ O, u16* __restrict__ Ob) {
  int row = blockIdx.x, tid = threadIdx.x;
  const float* a = A + (size_t)row * DD;
  const float* b = Bv + (size_t)row * DD;
  __shared__ float red[256];
  float v[4]; float s = 0.f;
  #pragma unroll
  for (int i = 0; i < 4; ++i) { v[i] = a[tid + (i << 8)] + b[tid + (i << 8)]; s += v[i]; }
  red[tid] = s; __syncthreads();
  for (int t = 128; t > 0; t >>= 1) { if (tid < t) red[tid] += red[tid + t]; __syncthreads(); }
  float mean = red[0] * (1.f / 1024.f);
  __syncthreads();
  float vs = 0.f;
  #pragma unroll
  for (int i = 0; i < 4; ++i) { float d = v[i] - mean; vs += d * d; }
  red[tid] = vs; __syncthreads();
  for (int t = 128; t > 0; t >>= 1) { if (tid < t) red[tid] += red[tid + t]; __syncthreads(); }
  float inv = rsqrtf(red[0] * (1.f / 1023.f));
  #pragma unroll
  for (int i = 0; i < 4; ++i) {
    float o = (v[i] - mean) * inv;
    O[(size_t)row * DD + tid + (i << 8)] = o;
    if (Ob) Ob[(size_t)row * DD + tid + (i << 8)] = f2bf(o);
  }
}

extern "C" void kernel_launch(void* const* d_in, const int* in_sizes, int n_in,
                              void* d_out, int out_size, void* d_ws, size_t ws_size,
                              hipStream_t stream) {
  (void)in_sizes; (void)n_in; (void)out_size; (void)ws_size;
  const float* x    = (const float*)d_in[0];
  const float* y    = (const float*)d_in[1];
  const float* Wq1  = (const float*)d_in[2];
  const float* Wk1  = (const float*)d_in[3];
  const float* Wv1  = (const float*)d_in[4];
  const float* Wo1  = (const float*)d_in[5];
  const float* Wq2  = (const float*)d_in[6];
  const float* Wk2  = (const float*)d_in[7];
  const float* Wv2  = (const float*)d_in[8];
  const float* Wo2  = (const float*)d_in[9];
  const float* w_in  = (const float*)d_in[10];
  const float* b_in  = (const float*)d_in[11];
  const float* w_out = (const float*)d_in[12];
  const float* b_out = (const float*)d_in[13];

  float* ws = (float*)d_ws;
  size_t off = 0;
  auto allocw = [&](size_t nw) { float* p = ws + off; off += nw; return p; };
  const size_t MR = (size_t)BB * TT;           // 4096
  const size_t ND = MR * DD;                   // 4.19M elems

  u16* Bq   = (u16*)allocw(512 * 1024);
  u16* Bk   = (u16*)allocw(512 * 1024);
  u16* Bv   = (u16*)allocw(512 * 1024);
  u16* Bwo  = (u16*)allocw(512 * 1024);
  u16* Wi   = (u16*)allocw(2 * 1024 * 1024);
  u16* Wob  = (u16*)allocw(2 * 1024 * 1024);
  u16* xbf  = (u16*)allocw(ND / 2);
  u16* ybf  = (u16*)allocw(ND / 2);
  u16* REG  = (u16*)allocw(ND * 2);
  float* ff2  = allocw(ND);
  float* out1 = allocw(ND);
  float* out2 = allocw(ND);
  float* cmax = allocw((size_t)BB * HH * TT);
  float* csum = allocw((size_t)BB * HH * TT);

  u16* Qb = REG;
  u16* Kb = REG + ND;
  u16* Vt = REG + 2 * ND;   // V transposed: col-major (1024 cols x 4096 rows), pitch 4096
  u16* Mb = REG + 3 * ND;   // mhaO; also hosts out1_bf between layers
  u16* ff1b = REG;
  u16* out2bf = ybf;

  dim3 blk(256);
  dim3 gConv(4096);
  dim3 gSm(1024);
  dim3 gRw(16, 16);
  dim3 gP(8, 32);
  dim3 gF1(32, 32);
  dim3 gAttn(BB * HH, TT / 64);
  dim3 gNorm(MR);

  hipMemcpyAsync(d_out, (const void*)x, ND * sizeof(float), hipMemcpyDeviceToDevice, stream);

  k_f2bf<<<gConv, blk, 0, stream>>>(y, ybf, (int)ND);
  k_f2bf<<<gConv, blk, 0, stream>>>(x, xbf, (int)ND);
  k_f2bf<<<gConv, blk, 0, stream>>>(w_in, Wi, FFF * DD);
  k_f2bf<<<gConv, blk, 0, stream>>>(w_out, Wob, DD * FFF);

  // ---- Layer 1: masked self-attention on y ----
  k_softmax_w_bf<<<gSm, blk, 0, stream>>>(Wq1, Bq);
  k_softmax_w_bf<<<gSm, blk, 0, stream>>>(Wk1, Bk);
  k_reorder_w_bf<<<gRw, blk, 0, stream>>>(Wv1, Bv);
  k_transpose_bf<<<gRw, blk, 0, stream>>>(Wo1, Bwo);
  k_mfma_nt<<<gP, blk, 0, stream>>>(ybf, Bq, nullptr, Qb, nullptr, nullptr, 0, 4096, 1024, 1024);
  k_mfma_nt<<<gP, blk, 0, stream>>>(ybf, Bk, nullptr, Kb, nullptr, nullptr, 0, 4096, 1024, 1024);
  k_mfma_nt<<<gP, blk, 0, stream>>>(ybf, Bv, nullptr, nullptr, Vt, nullptr, 0, 4096, 1024, 1024);
  k_attn_stats_mfma<<<gAttn, blk, 0, stream>>>(Qb, Kb, cmax, csum);
  k_attn_apply_mfma<<<gAttn, blk, 0, stream>>>(Qb, Kb, Vt, cmax, csum, Mb);
  k_mfma_nt<<<gP, blk, 0, stream>>>(Mb, Bwo, ff2, nullptr, nullptr, nullptr, 0, 4096, 1024, 1024);
  k_add_norm<<<gNorm, blk, 0, stream>>>(ff2, y, out1, Mb /* out1_bf */);

  // ---- Layer 2: cross-attention (Q from out1, K/V from x) ----
  k_reorder_w_bf<<<gRw, blk, 0, stream>>>(Wq2, Bq);
  k_reorder_w_bf<<<gRw, blk, 0, stream>>>(Wk2, Bk);
  k_reorder_w_bf<<<gRw, blk, 0, stream>>>(Wv2, Bv);
  k_transpose_bf<<<gRw, blk, 0, stream>>>(Wo2, Bwo);
  k_mfma_nt<<<gP, blk, 0, stream>>>(Mb /* out1_bf */, Bq, nullptr, Qb, nullptr, nullptr, 0, 4096, 1024, 1024);
  k_mfma_nt<<<gP, blk, 0, stream>>>(xbf, Bk, nullptr, Kb, nullptr, nullptr, 0, 4096, 1024, 1024);
  k_mfma_nt<<<gP, blk, 0, stream>>>(xbf, Bv, nullptr, nullptr, Vt, nullptr, 0, 4096, 1024, 1024);
  k_attn_stats_mfma<<<gAttn, blk, 0, stream>>>(Qb, Kb, cmax, csum);
  k_attn_apply_mfma<<<gAttn, blk, 0, stream>>>(Qb, Kb, Vt, cmax, csum, Mb);
  k_mfma_nt<<<gP, blk, 0, stream>>>(Mb, Bwo, ff2, nullptr, nullptr, nullptr, 0, 4096, 1024, 1024);
  k_add_norm<<<gNorm, blk, 0, stream>>>(ff2, out1, out2, out2bf);

  // ---- FF ----
  k_mfma_nt<<<gF1, blk, 0, stream>>>(out2bf, Wi, nullptr, ff1b, nullptr, b_in, 1, 4096, 4096, 1024);
  k_mfma_nt<<<gP, blk, 0, stream>>>(ff1b, Wob, ff2, nullptr, nullptr, b_out, 0, 4096, 1024, 4096);
  k_add_norm<<<gNorm, blk, 0, stream>>>(ff2, out2, (float*)d_out + ND, nullptr);
}

// Round 4
// 500.738 us; speedup vs baseline: 9.8164x; 1.2177x over previous
//
#include <hip/hip_runtime.h>
#include <hip/hip_bf16.h>

#define BB 4
#define TT 1024
#define DD 1024
#define HH 16
#define DKK 64
#define FFF 4096

typedef unsigned short u16;
typedef unsigned int u32;
typedef __attribute__((ext_vector_type(8))) short s16x8;
typedef __attribute__((ext_vector_type(4))) float f32x4;

static __device__ __forceinline__ float bf2f(u16 s) {
  union { u32 u; float f; } v; v.u = ((u32)s) << 16; return v.f;
}
static __device__ __forceinline__ u16 f2bf(float f) {
  union { float f; u32 u; } v; v.f = f;
  u32 r = v.u + 0x7FFFu + ((v.u >> 16) & 1u);
  return (u16)(r >> 16);
}

#define GLDS(gp, lp) __builtin_amdgcn_global_load_lds( \
    (const __attribute__((address_space(1))) u32*)(gp), \
    (__attribute__((address_space(3))) u32*)(lp), 16, 0, 0)

// XCD-chunked bijective block swizzle: contiguous work per XCD, 8-row supertiles.
// Requires gridDim.y % 8 == 0 and nwg % 8 == 0 (all our grids satisfy this).
static __device__ __forceinline__ void swz_block(int& bx, int& by) {
  int gx = gridDim.x, gy = gridDim.y;
  int nwg = gx * gy;
  int orig = by * gx + bx;
  int q = nwg >> 3, r = nwg & 7;
  int xcd = orig & 7, sl = orig >> 3;
  int wgid = (xcd < r ? xcd * (q + 1) : r * (q + 1) + (xcd - r) * q) + sl;
  int g = gx << 3;
  int grp = wgid / g, rem = wgid % g;
  bx = rem >> 3;
  by = (grp << 3) + (rem & 7);
}

// ---------------- f32 -> bf16 elementwise ----------------
__global__ __launch_bounds__(256) void k_f2bf(const float* __restrict__ s, u16* __restrict__ d, int n) {
  int i = (blockIdx.x * 256 + threadIdx.x) * 4;
  if (i < n) {
    float4 v = *(const float4*)(s + i);
    u16 o[4] = { f2bf(v.x), f2bf(v.y), f2bf(v.z), f2bf(v.w) };
    *(ushort4*)(d + i) = *(ushort4*)o;
  }
}

// ---------------- masked softmax over d (axis -2), write bf16 B[n= h*64+k][d] ----------------
__global__ __launch_bounds__(256) void k_softmax_w_bf(const float* __restrict__ W, u16* __restrict__ Bt) {
  int col = blockIdx.x;           // h*64 + k
  int h = col >> 6, k = col & 63;
  int tid = threadIdx.x;
  const float* w = W + ((size_t)h * DD) * DKK + k;
  __shared__ float red[256];
  float m = -1e30f;
  for (int d = k + tid; d < DD; d += 256) m = fmaxf(m, w[(size_t)d * DKK]);
  red[tid] = m; __syncthreads();
  for (int s = 128; s > 0; s >>= 1) { if (tid < s) red[tid] = fmaxf(red[tid], red[tid + s]); __syncthreads(); }
  m = red[0]; __syncthreads();
  float sum = 0.f;
  for (int d = k + tid; d < DD; d += 256) sum += __expf(w[(size_t)d * DKK] - m);
  red[tid] = sum; __syncthreads();
  for (int s = 128; s > 0; s >>= 1) { if (tid < s) red[tid] += red[tid + s]; __syncthreads(); }
  float inv = 1.f / red[0];
  for (int d = tid; d < DD; d += 256) {
    float v = (d >= k) ? __expf(w[(size_t)d * DKK] - m) * inv : 0.f;
    Bt[(size_t)col * DD + d] = f2bf(v);
  }
}

// ---------------- reorder (H, D, DK) -> bf16 B[n=h*64+k][d] ----------------
__global__ __launch_bounds__(256) void k_reorder_w_bf(const float* __restrict__ W, u16* __restrict__ Bt) {
  int d0 = blockIdx.x << 6, h = blockIdx.y;
  __shared__ float t[64][65];
  int tid = threadIdx.x;
  const float* src = W + (size_t)h * DD * DKK + (size_t)d0 * DKK;
  #pragma unroll
  for (int i = 0; i < 16; ++i) {
    int e = i * 256 + tid; int r = e >> 6, c = e & 63;
    t[r][c] = src[(size_t)r * DKK + c];
  }
  __syncthreads();
  #pragma unroll
  for (int i = 0; i < 16; ++i) {
    int e = i * 256 + tid; int c = e >> 6, r = e & 63;
    Bt[((size_t)(h * 64 + c)) * DD + d0 + r] = f2bf(t[r][c]);
  }
}

// ---------------- transpose (K,N) f32 -> bf16 B[n][k] ----------------
__global__ __launch_bounds__(256) void k_transpose_bf(const float* __restrict__ W, u16* __restrict__ Bt) {
  int k0 = blockIdx.x << 6, n0 = blockIdx.y << 6;
  __shared__ float t[64][65];
  int tid = threadIdx.x;
  #pragma unroll
  for (int i = 0; i < 16; ++i) {
    int e = i * 256 + tid; int r = e >> 6, c = e & 63;
    t[r][c] = W[(size_t)(k0 + r) * DD + n0 + c];
  }
  __syncthreads();
  #pragma unroll
  for (int i = 0; i < 16; ++i) {
    int e = i * 256 + tid; int c = e >> 6, r = e & 63;
    Bt[(size_t)(n0 + c) * DD + k0 + r] = f2bf(t[r][c]);
  }
}

// ---------------- MFMA NT GEMM: C(MxN) = A(MxK) * B(NxK)^T (bf16 in, f32 acc) ----------------
// 128x128 tile, BK=32, 2-phase double-buffered LDS, XCD swizzle.
// mode 0: Cf (f32) / Cb (bf16) row-major + bias/relu.
// mode 1 (QKV, N=3072): col<1024 -> Cb, <2048 -> Cb2, else col-major Ct (pitch M).
// mode 2 (KV,  N=2048): col<1024 -> Cb, else col-major Ct.
__global__ __launch_bounds__(256) void k_mfma_nt(
    const u16* __restrict__ A, const u16* __restrict__ B,
    float* __restrict__ Cf, u16* __restrict__ Cb, u16* __restrict__ Cb2, u16* __restrict__ Ct,
    const float* __restrict__ bias, int relu, int mode, int M, int N, int K) {
  __shared__ u16 As[2 * 128 * 32];
  __shared__ u16 Bs[2 * 128 * 32];
  int bx = blockIdx.x, by = blockIdx.y;
  swz_block(bx, by);
  int tid = threadIdx.x, wave = tid >> 6, lane = tid & 63;
  int row0 = by << 7, col0 = bx << 7;
  int wm = (wave >> 1) << 6, wn = (wave & 1) << 6;

  f32x4 acc[4][4];
  #pragma unroll
  for (int m = 0; m < 4; ++m)
    #pragma unroll
    for (int n = 0; n < 4; ++n) acc[m][n] = f32x4{0.f, 0.f, 0.f, 0.f};

  int c0 = wave * 2, c1 = wave * 2 + 1;
  int r0 = (c0 << 4) + (lane >> 2);
  int r1 = (c1 << 4) + (lane >> 2);
  int ce = (lane & 3) << 3;
  const u16* Ag0 = A + (size_t)(row0 + r0) * K + ce;
  const u16* Ag1 = A + (size_t)(row0 + r1) * K + ce;
  const u16* Bg0 = B + (size_t)(col0 + r0) * K + ce;
  const u16* Bg1 = B + (size_t)(col0 + r1) * K + ce;

  int fr = lane & 15, kg = (lane >> 4) << 3;
  int ardo = (wm + fr) * 32 + kg;
  int brdo = (wn + fr) * 32 + kg;

  auto STAGE = [&](int buf, int k0) {
    u16* Ab = As + buf * 4096;
    u16* Bb = Bs + buf * 4096;
    GLDS(Ag0 + k0, Ab + c0 * 512);
    GLDS(Ag1 + k0, Ab + c1 * 512);
    GLDS(Bg0 + k0, Bb + c0 * 512);
    GLDS(Bg1 + k0, Bb + c1 * 512);
  };

  STAGE(0, 0);
  __syncthreads();
  int cur = 0;
  for (int k0 = 0; k0 < K; k0 += 32) {
    int nxt = k0 + 32;
    if (nxt < K) STAGE(cur ^ 1, nxt);      // loads for t+1 fly under MFMA of t
    const u16* Ard = As + cur * 4096 + ardo;
    const u16* Brd = Bs + cur * 4096 + brdo;
    s16x8 aF[4], bF[4];
    #pragma unroll
    for (int m = 0; m < 4; ++m) aF[m] = *(const s16x8*)(Ard + m * 16 * 32);
    #pragma unroll
    for (int n = 0; n < 4; ++n) bF[n] = *(const s16x8*)(Brd + n * 16 * 32);
    #pragma unroll
    for (int m = 0; m < 4; ++m)
      #pragma unroll
      for (int n = 0; n < 4; ++n)
        acc[m][n] = __builtin_amdgcn_mfma_f32_16x16x32_bf16(aF[m], bF[n], acc[m][n], 0, 0, 0);
    __syncthreads();                        // vmcnt(0)+barrier: next buf ready, cur free
    cur ^= 1;
  }

  int fq = (lane >> 4) << 2;
  #pragma unroll
  for (int n = 0; n < 4; ++n) {
    int col = col0 + wn + n * 16 + fr;
    float bs = bias ? bias[col] : 0.f;
    #pragma unroll
    for (int m = 0; m < 4; ++m) {
      float v[4];
      #pragma unroll
      for (int r = 0; r < 4; ++r) {
        v[r] = acc[m][n][r] + bs;
        if (relu) v[r] = fmaxf(v[r], 0.f);
      }
      int rowb = row0 + wm + m * 16 + fq;
      if (mode == 0) {
        if (Cf) {
          #pragma unroll
          for (int r = 0; r < 4; ++r) Cf[(size_t)(rowb + r) * N + col] = v[r];
        }
        if (Cb) {
          #pragma unroll
          for (int r = 0; r < 4; ++r) Cb[(size_t)(rowb + r) * N + col] = f2bf(v[r]);
        }
      } else {
        int q = col >> 10, lc = col & 1023;
        u16* dstRM = nullptr;
        if (mode == 1) dstRM = (q == 0) ? Cb : ((q == 1) ? Cb2 : nullptr);
        else           dstRM = (q == 0) ? Cb : nullptr;
        if (dstRM) {
          #pragma unroll
          for (int r = 0; r < 4; ++r) dstRM[(size_t)(rowb + r) * 1024 + lc] = f2bf(v[r]);
        } else {
          u16 pb[4] = { f2bf(v[0]), f2bf(v[1]), f2bf(v[2]), f2bf(v[3]) };
          uint2 wv; wv.x = (u32)pb[0] | ((u32)pb[1] << 16); wv.y = (u32)pb[2] | ((u32)pb[3] << 16);
          *(uint2*)(Ct + (size_t)lc * 4096 + rowb) = wv;
        }
      }
    }
  }
}

// ---------------- stage 64x64 bf16 (global pitch gp) -> padded LDS [64][72] ----------------
static __device__ __forceinline__ void stage_pad(const u16* __restrict__ g, int gp, u16* L, int tid) {
  #pragma unroll
  for (int i = 0; i < 2; ++i) {
    int c = (i << 8) + tid;                 // 0..511 chunks of 8
    int row = c >> 3, col8 = (c & 7) << 3;
    uint4 v = *(const uint4*)(g + (size_t)row * gp + col8);
    *(uint4*)(L + row * 72 + col8) = v;
  }
}

// ---------------- attention pass 1 (MFMA): per-(bh,s) max & sum over t ----------------
__global__ __launch_bounds__(256) void k_attn_stats_mfma(const u16* __restrict__ Qb, const u16* __restrict__ Kb,
                                                         float* __restrict__ cmax, float* __restrict__ csum) {
  __shared__ u16 Ks[64 * 72];
  __shared__ u16 Qs[64 * 72];
  int tid = threadIdx.x, wave = tid >> 6, lane = tid & 63;
  int bh = blockIdx.x, b = bh >> 4, h = bh & 15;
  int s0 = blockIdx.y << 6;
  stage_pad(Kb + ((size_t)(b * TT + s0)) * DD + h * 64, DD, Ks, tid);
  __syncthreads();
  int fr = lane & 15, g = lane >> 4;
  const u16* Bbase = Ks + (wave * 16 + fr) * 72 + g * 8;
  const u16* Abase = Qs + fr * 72 + g * 8;
  s16x8 bF0 = *(const s16x8*)(Bbase);
  s16x8 bF1 = *(const s16x8*)(Bbase + 32);
  float m = -1e30f, sum = 0.f;
  for (int t0 = 0; t0 < TT; t0 += 64) {
    __syncthreads();
    stage_pad(Qb + ((size_t)(b * TT + t0)) * DD + h * 64, DD, Qs, tid);
    __syncthreads();
    #pragma unroll
    for (int mt = 0; mt < 4; ++mt) {
      f32x4 acc = f32x4{0.f, 0.f, 0.f, 0.f};
      s16x8 a0 = *(const s16x8*)(Abase + mt * 16 * 72);
      s16x8 a1 = *(const s16x8*)(Abase + mt * 16 * 72 + 32);
      acc = __builtin_amdgcn_mfma_f32_16x16x32_bf16(a0, bF0, acc, 0, 0, 0);
      acc = __builtin_amdgcn_mfma_f32_16x16x32_bf16(a1, bF1, acc, 0, 0, 0);
      float v0 = acc[0] * 0.125f, v1 = acc[1] * 0.125f, v2 = acc[2] * 0.125f, v3 = acc[3] * 0.125f;
      float tm = fmaxf(fmaxf(v0, v1), fmaxf(v2, v3));
      float nm = fmaxf(m, tm);
      sum = sum * __expf(m - nm) + __expf(v0 - nm) + __expf(v1 - nm) + __expf(v2 - nm) + __expf(v3 - nm);
      m = nm;
    }
  }
  #pragma unroll
  for (int mask = 16; mask <= 32; mask <<= 1) {
    float m2 = __shfl_xor(m, mask, 64);
    float s2 = __shfl_xor(sum, mask, 64);
    float nm = fmaxf(m, m2);
    sum = sum * __expf(m - nm) + s2 * __expf(m2 - nm);
    m = nm;
  }
  if (lane < 16) {
    size_t o = (size_t)bh * TT + s0 + wave * 16 + lane;
    cmax[o] = m; csum[o] = sum;
  }
}

// ---------------- attention pass 2 (MFMA) ----------------
__global__ __launch_bounds__(256) void k_attn_apply_mfma(const u16* __restrict__ Qb, const u16* __restrict__ Kb,
                                                         const u16* __restrict__ Vt,
                                                         const float* __restrict__ cmax, const float* __restrict__ csum,
                                                         u16* __restrict__ Op) {
  __shared__ u16 Qs[64 * 72];
  __shared__ u16 Ks[64 * 72];
  __shared__ u16 VTs[64 * 72];
  __shared__ u16 Pl[4 * 1024];
  __shared__ float cmL[64];
  __shared__ float rcsL[64];
  int tid = threadIdx.x, wave = tid >> 6, lane = tid & 63;
  int bh = blockIdx.x, b = bh >> 4, h = bh & 15;
  int t0 = blockIdx.y << 6;
  stage_pad(Qb + ((size_t)(b * TT + t0)) * DD + h * 64, DD, Qs, tid);
  __syncthreads();
  int fr = lane & 15, g = lane >> 4;
  const u16* QbF = Qs + (wave * 16 + fr) * 72 + g * 8;
  const u16* KaF = Ks + fr * 72 + g * 8;
  char* Pw = (char*)(Pl + wave * 1024);
  uint swz = ((uint)(lane & 7)) << 4;
  s16x8 qF0 = *(const s16x8*)(QbF);
  s16x8 qF1 = *(const s16x8*)(QbF + 32);
  f32x4 acc_o[4];
  #pragma unroll
  for (int nt = 0; nt < 4; ++nt) acc_o[nt] = f32x4{0.f, 0.f, 0.f, 0.f};
  const size_t cbase = (size_t)bh * TT;

  for (int s0 = 0; s0 < TT; s0 += 64) {
    __syncthreads();
    stage_pad(Kb + ((size_t)(b * TT + s0)) * DD + h * 64, DD, Ks, tid);
    stage_pad(Vt + (size_t)(h * 64) * 4096 + (size_t)b * TT + s0, 4096, VTs, tid);
    if (tid < 64) cmL[tid] = cmax[cbase + s0 + tid];
    else if (tid < 128) rcsL[tid - 64] = 1.f / csum[cbase + s0 + tid - 64];
    __syncthreads();
    #pragma unroll
    for (int mt = 0; mt < 4; ++mt) {
      f32x4 acc = f32x4{0.f, 0.f, 0.f, 0.f};
      s16x8 a0 = *(const s16x8*)(KaF + mt * 16 * 72);
      s16x8 a1 = *(const s16x8*)(KaF + mt * 16 * 72 + 32);
      acc = __builtin_amdgcn_mfma_f32_16x16x32_bf16(a0, qF0, acc, 0, 0, 0);
      acc = __builtin_amdgcn_mfma_f32_16x16x32_bf16(a1, qF1, acc, 0, 0, 0);
      f32x4 cm4 = *(const f32x4*)&cmL[mt * 16 + g * 4];
      f32x4 rc4 = *(const f32x4*)&rcsL[mt * 16 + g * 4];
      u16 pb[4];
      #pragma unroll
      for (int r = 0; r < 4; ++r)
        pb[r] = f2bf(__expf(acc[r] * 0.125f - cm4[r]) * rc4[r]);
      uint woff = (uint)fr * 128 + (uint)(mt * 16 + g * 4) * 2;
      uint2 wv; wv.x = (u32)pb[0] | ((u32)pb[1] << 16); wv.y = (u32)pb[2] | ((u32)pb[3] << 16);
      *(uint2*)(Pw + (woff ^ swz)) = wv;
    }
    uint rbase = (uint)fr * 128;
    s16x8 pF0 = *(const s16x8*)(Pw + ((rbase + g * 16) ^ swz));
    s16x8 pF1 = *(const s16x8*)(Pw + ((rbase + 64 + g * 16) ^ swz));
    #pragma unroll
    for (int nt = 0; nt < 4; ++nt) {
      s16x8 v0 = *(const s16x8*)(VTs + (nt * 16 + fr) * 72 + g * 8);
      s16x8 v1 = *(const s16x8*)(VTs + (nt * 16 + fr) * 72 + 32 + g * 8);
      acc_o[nt] = __builtin_amdgcn_mfma_f32_16x16x32_bf16(pF0, v0, acc_o[nt], 0, 0, 0);
      acc_o[nt] = __builtin_amdgcn_mfma_f32_16x16x32_bf16(pF1, v1, acc_o[nt], 0, 0, 0);
    }
  }
  int tg = t0 + wave * 16 + g * 4;
  #pragma unroll
  for (int nt = 0; nt < 4; ++nt) {
    #pragma unroll
    for (int r = 0; r < 4; ++r) {
      Op[((size_t)(b * TT + tg + r)) * DD + h * 64 + nt * 16 + fr] = f2bf(acc_o[nt][r]);
    }
  }
}

// ---------------- O = norm(A + Bv) per row of 1024; optional bf16 copy ----------------
__global__ __launch_bounds__(256) void k_add_norm(const float* __restrict__ A, const float* __restrict__ Bv,
                                                  float* __restrict__ O, u16* __restrict__ Ob) {
  int row = blockIdx.x, tid = threadIdx.x;
  const float* a = A + (size_t)row * DD;
  const float* b = Bv + (size_t)row * DD;
  __shared__ float red[256];
  float v[4]; float s = 0.f;
  #pragma unroll
  for (int i = 0; i < 4; ++i) { v[i] = a[tid + (i << 8)] + b[tid + (i << 8)]; s += v[i]; }
  red[tid] = s; __syncthreads();
  for (int t = 128; t > 0; t >>= 1) { if (tid < t) red[tid] += red[tid + t]; __syncthreads(); }
  float mean = red[0] * (1.f / 1024.f);
  __syncthreads();
  float vs = 0.f;
  #pragma unroll
  for (int i = 0; i < 4; ++i) { float d = v[i] - mean; vs += d * d; }
  red[tid] = vs; __syncthreads();
  for (int t = 128; t > 0; t >>= 1) { if (tid < t) red[tid] += red[tid + t]; __syncthreads(); }
  float inv = rsqrtf(red[0] * (1.f / 1023.f));
  #pragma unroll
  for (int i = 0; i < 4; ++i) {
    float o = (v[i] - mean) * inv;
    O[(size_t)row * DD + tid + (i << 8)] = o;
    if (Ob) Ob[(size_t)row * DD + tid + (i << 8)] = f2bf(o);
  }
}

extern "C" void kernel_launch(void* const* d_in, const int* in_sizes, int n_in,
                              void* d_out, int out_size, void* d_ws, size_t ws_size,
                              hipStream_t stream) {
  (void)in_sizes; (void)n_in; (void)out_size; (void)ws_size;
  const float* x    = (const float*)d_in[0];
  const float* y    = (const float*)d_in[1];
  const float* Wq1  = (const float*)d_in[2];
  const float* Wk1  = (const float*)d_in[3];
  const float* Wv1  = (const float*)d_in[4];
  const float* Wo1  = (const float*)d_in[5];
  const float* Wq2  = (const float*)d_in[6];
  const float* Wk2  = (const float*)d_in[7];
  const float* Wv2  = (const float*)d_in[8];
  const float* Wo2  = (const float*)d_in[9];
  const float* w_in  = (const float*)d_in[10];
  const float* b_in  = (const float*)d_in[11];
  const float* w_out = (const float*)d_in[12];
  const float* b_out = (const float*)d_in[13];

  float* ws = (float*)d_ws;
  size_t off = 0;
  auto allocw = [&](size_t nw) { float* p = ws + off; off += nw; return p; };
  const size_t MR = (size_t)BB * TT;           // 4096
  const size_t ND = MR * DD;                   // 4.19M elems

  u16* Bq   = (u16*)allocw(512 * 1024);        // Bq|Bk|Bv contiguous => fused B (3072 x 1024)
  u16* Bk   = (u16*)allocw(512 * 1024);
  u16* Bv   = (u16*)allocw(512 * 1024);
  u16* Bwo  = (u16*)allocw(512 * 1024);
  u16* Wi   = (u16*)allocw(2 * 1024 * 1024);
  u16* Wob  = (u16*)allocw(2 * 1024 * 1024);
  u16* xbf  = (u16*)allocw(ND / 2);
  u16* ybf  = (u16*)allocw(ND / 2);
  u16* REG  = (u16*)allocw(ND * 2);
  float* ff2  = allocw(ND);
  float* out1 = allocw(ND);
  float* out2 = allocw(ND);
  float* cmax = allocw((size_t)BB * HH * TT);
  float* csum = allocw((size_t)BB * HH * TT);

  u16* Qb = REG;
  u16* Kb = REG + ND;
  u16* Vt = REG + 2 * ND;   // V col-major (1024 x 4096), pitch 4096
  u16* Mb = REG + 3 * ND;   // mhaO; also out1_bf between layers
  u16* ff1b = REG;
  u16* out2bf = ybf;

  dim3 blk(256);
  dim3 gConv(4096);
  dim3 gSm(1024);
  dim3 gRw(16, 16);
  dim3 gQKV(24, 32);        // N=3072
  dim3 gKV(16, 32);         // N=2048
  dim3 gP(8, 32);           // N=1024
  dim3 gF1(32, 32);         // N=4096
  dim3 gAttn(BB * HH, TT / 64);
  dim3 gNorm(MR);

  hipMemcpyAsync(d_out, (const void*)x, ND * sizeof(float), hipMemcpyDeviceToDevice, stream);

  k_f2bf<<<gConv, blk, 0, stream>>>(y, ybf, (int)ND);
  k_f2bf<<<gConv, blk, 0, stream>>>(x, xbf, (int)ND);
  k_f2bf<<<gConv, blk, 0, stream>>>(w_in, Wi, FFF * DD);
  k_f2bf<<<gConv, blk, 0, stream>>>(w_out, Wob, DD * FFF);

  // ---- Layer 1: masked self-attention on y ----
  k_softmax_w_bf<<<gSm, blk, 0, stream>>>(Wq1, Bq);
  k_softmax_w_bf<<<gSm, blk, 0, stream>>>(Wk1, Bk);
  k_reorder_w_bf<<<gRw, blk, 0, stream>>>(Wv1, Bv);
  k_transpose_bf<<<gRw, blk, 0, stream>>>(Wo1, Bwo);
  // fused QKV projection: A=ybf, B=[Bq|Bk|Bv], outputs Qb,Kb row-major + Vt col-major
  k_mfma_nt<<<gQKV, blk, 0, stream>>>(ybf, Bq, nullptr, Qb, Kb, Vt, nullptr, 0, 1, 4096, 3072, 1024);
  k_attn_stats_mfma<<<gAttn, blk, 0, stream>>>(Qb, Kb, cmax, csum);
  k_attn_apply_mfma<<<gAttn, blk, 0, stream>>>(Qb, Kb, Vt, cmax, csum, Mb);
  k_mfma_nt<<<gP, blk, 0, stream>>>(Mb, Bwo, ff2, nullptr, nullptr, nullptr, nullptr, 0, 0, 4096, 1024, 1024);
  k_add_norm<<<gNorm, blk, 0, stream>>>(ff2, y, out1, Mb /* out1_bf */);

  // ---- Layer 2: cross-attention (Q from out1, K/V from x) ----
  k_reorder_w_bf<<<gRw, blk, 0, stream>>>(Wq2, Bq);
  k_reorder_w_bf<<<gRw, blk, 0, stream>>>(Wk2, Bk);
  k_reorder_w_bf<<<gRw, blk, 0, stream>>>(Wv2, Bv);
  k_transpose_bf<<<gRw, blk, 0, stream>>>(Wo2, Bwo);
  k_mfma_nt<<<gP, blk, 0, stream>>>(Mb /* out1_bf */, Bq, nullptr, Qb, nullptr, nullptr, nullptr, 0, 0, 4096, 1024, 1024);
  // fused KV projection: A=xbf, B=[Bk|Bv], outputs Kb row-major + Vt col-major
  k_mfma_nt<<<gKV, blk, 0, stream>>>(xbf, Bk, nullptr, Kb, nullptr, Vt, nullptr, 0, 2, 4096, 2048, 1024);
  k_attn_stats_mfma<<<gAttn, blk, 0, stream>>>(Qb, Kb, cmax, csum);
  k_attn_apply_mfma<<<gAttn, blk, 0, stream>>>(Qb, Kb, Vt, cmax, csum, Mb);
  k_mfma_nt<<<gP, blk, 0, stream>>>(Mb, Bwo, ff2, nullptr, nullptr, nullptr, nullptr, 0, 0, 4096, 1024, 1024);
  k_add_norm<<<gNorm, blk, 0, stream>>>(ff2, out1, out2, out2bf);

  // ---- FF ----
  k_mfma_nt<<<gF1, blk, 0, stream>>>(out2bf, Wi, nullptr, ff1b, nullptr, nullptr, b_in, 1, 0, 4096, 4096, 1024);
  k_mfma_nt<<<gP, blk, 0, stream>>>(ff1b, Wob, ff2, nullptr, nullptr, nullptr, b_out, 0, 0, 4096, 1024, 4096);
  k_add_norm<<<gNorm, blk, 0, stream>>>(ff2, out2, (float*)d_out + ND, nullptr);
}

// Round 5
// 455.593 us; speedup vs baseline: 10.7891x; 1.0991x over previous
//
#include <hip/hip_runtime.h>
#include <hip/hip_bf16.h>

#define BB 4
#define TT 1024
#define DD 1024
#define HH 16
#define DKK 64
#define FFF 4096

typedef unsigned short u16;
typedef unsigned int u32;
typedef __attribute__((ext_vector_type(8))) short s16x8;
typedef __attribute__((ext_vector_type(4))) float f32x4;

static __device__ __forceinline__ float bf2f(u16 s) {
  union { u32 u; float f; } v; v.u = ((u32)s) << 16; return v.f;
}
static __device__ __forceinline__ u16 f2bf(float f) {
  union { float f; u32 u; } v; v.f = f;
  u32 r = v.u + 0x7FFFu + ((v.u >> 16) & 1u);
  return (u16)(r >> 16);
}

#define GLDS(gp, lp) __builtin_amdgcn_global_load_lds( \
    (const __attribute__((address_space(1))) u32*)(gp), \
    (__attribute__((address_space(3))) u32*)(lp), 16, 0, 0)

// XCD-chunked bijective block swizzle (m204 formula), 8-row supertiles.
static __device__ __forceinline__ void swz_block(int& bx, int& by) {
  int gx = gridDim.x, gy = gridDim.y;
  int nwg = gx * gy;
  int orig = by * gx + bx;
  int q = nwg >> 3, r = nwg & 7;
  int xcd = orig & 7, sl = orig >> 3;
  int wgid = (xcd < r ? xcd * (q + 1) : r * (q + 1) + (xcd - r) * q) + sl;
  int g = gx << 3;
  int grp = wgid / g, rem = wgid % g;
  bx = rem >> 3;
  by = (grp << 3) + (rem & 7);
}

// ---------------- f32 -> bf16 elementwise ----------------
__global__ __launch_bounds__(256) void k_f2bf(const float* __restrict__ s, u16* __restrict__ d, int n) {
  int i = (blockIdx.x * 256 + threadIdx.x) * 4;
  if (i < n) {
    float4 v = *(const float4*)(s + i);
    u16 o[4] = { f2bf(v.x), f2bf(v.y), f2bf(v.z), f2bf(v.w) };
    *(ushort4*)(d + i) = *(ushort4*)o;
  }
}

// ---------------- masked softmax over d (axis -2), write bf16 B[n= h*64+k][d] ----------------
__global__ __launch_bounds__(256) void k_softmax_w_bf(const float* __restrict__ W, u16* __restrict__ Bt) {
  int col = blockIdx.x;           // h*64 + k
  int h = col >> 6, k = col & 63;
  int tid = threadIdx.x;
  const float* w = W + ((size_t)h * DD) * DKK + k;
  __shared__ float red[256];
  float m = -1e30f;
  for (int d = k + tid; d < DD; d += 256) m = fmaxf(m, w[(size_t)d * DKK]);
  red[tid] = m; __syncthreads();
  for (int s = 128; s > 0; s >>= 1) { if (tid < s) red[tid] = fmaxf(red[tid], red[tid + s]); __syncthreads(); }
  m = red[0]; __syncthreads();
  float sum = 0.f;
  for (int d = k + tid; d < DD; d += 256) sum += __expf(w[(size_t)d * DKK] - m);
  red[tid] = sum; __syncthreads();
  for (int s = 128; s > 0; s >>= 1) { if (tid < s) red[tid] += red[tid + s]; __syncthreads(); }
  float inv = 1.f / red[0];
  for (int d = tid; d < DD; d += 256) {
    float v = (d >= k) ? __expf(w[(size_t)d * DKK] - m) * inv : 0.f;
    Bt[(size_t)col * DD + d] = f2bf(v);
  }
}

// ---------------- reorder (H, D, DK) -> bf16 B[n=h*64+k][d] ----------------
__global__ __launch_bounds__(256) void k_reorder_w_bf(const float* __restrict__ W, u16* __restrict__ Bt) {
  int d0 = blockIdx.x << 6, h = blockIdx.y;
  __shared__ float t[64][65];
  int tid = threadIdx.x;
  const float* src = W + (size_t)h * DD * DKK + (size_t)d0 * DKK;
  #pragma unroll
  for (int i = 0; i < 16; ++i) {
    int e = i * 256 + tid; int r = e >> 6, c = e & 63;
    t[r][c] = src[(size_t)r * DKK + c];
  }
  __syncthreads();
  #pragma unroll
  for (int i = 0; i < 16; ++i) {
    int e = i * 256 + tid; int c = e >> 6, r = e & 63;
    Bt[((size_t)(h * 64 + c)) * DD + d0 + r] = f2bf(t[r][c]);
  }
}

// ---------------- transpose (K,N) f32 -> bf16 B[n][k] ----------------
__global__ __launch_bounds__(256) void k_transpose_bf(const float* __restrict__ W, u16* __restrict__ Bt) {
  int k0 = blockIdx.x << 6, n0 = blockIdx.y << 6;
  __shared__ float t[64][65];
  int tid = threadIdx.x;
  #pragma unroll
  for (int i = 0; i < 16; ++i) {
    int e = i * 256 + tid; int r = e >> 6, c = e & 63;
    t[r][c] = W[(size_t)(k0 + r) * DD + n0 + c];
  }
  __syncthreads();
  #pragma unroll
  for (int i = 0; i < 16; ++i) {
    int e = i * 256 + tid; int c = e >> 6, r = e & 63;
    Bt[(size_t)(n0 + c) * DD + k0 + r] = f2bf(t[r][c]);
  }
}

// ---------------- MFMA NT GEMM: C = A(MxK) * B(NxK)^T (bf16 in, f32 acc) ----------------
// 128x128 tile, BK=32, 512 threads (8 waves 2x4, wave-tile 64x32), 2-phase dbuf LDS,
// XCD swizzle, optional split-K via blockIdx.z (partial z=0 -> Cf, z=1 -> Cf2, ...).
// mode 0: Cf/Cf2.. (f32 partials) or Cb (bf16) row-major + bias/relu.
// mode 1 (QKV, N=3072): col<1024 -> Cb, <2048 -> Cb2, else col-major Ct (pitch M).
// mode 2 (KV,  N=2048): col<1024 -> Cb, else col-major Ct.
__global__ __launch_bounds__(512) void k_mfma_nt(
    const u16* __restrict__ A, const u16* __restrict__ B,
    float* __restrict__ Cf, float* __restrict__ Cf2, float* __restrict__ Cf3, float* __restrict__ Cf4,
    u16* __restrict__ Cb, u16* __restrict__ Cb2, u16* __restrict__ Ct,
    const float* __restrict__ bias, int relu, int mode, int M, int N, int K) {
  __shared__ u16 As[2 * 128 * 32];
  __shared__ u16 Bs[2 * 128 * 32];
  int bx = blockIdx.x, by = blockIdx.y;
  swz_block(bx, by);
  int tid = threadIdx.x, wave = tid >> 6, lane = tid & 63;
  int row0 = by << 7, col0 = bx << 7;
  int wm = (wave >> 2) << 6;        // 0 / 64
  int wn = (wave & 3) << 5;         // 0 / 32 / 64 / 96

  int Ks = K / gridDim.z;
  int kbase = blockIdx.z * Ks;
  int kend = kbase + Ks;

  f32x4 acc[4][2];
  #pragma unroll
  for (int m = 0; m < 4; ++m)
    #pragma unroll
    for (int n = 0; n < 2; ++n) acc[m][n] = f32x4{0.f, 0.f, 0.f, 0.f};

  // staging: [128][32] bf16 = 8 KB per matrix; 512 threads x 16 B = exactly one GLDS each
  int srow = tid >> 2, scol = (tid & 3) << 3;
  const u16* Ag = A + (size_t)(row0 + srow) * K + scol;
  const u16* Bg = B + (size_t)(col0 + srow) * K + scol;
  int wbase = wave << 9;            // u16 offset of this wave's 1024 B chunk

  int fr = lane & 15, kg = (lane >> 4) << 3;
  int ardo = (wm + fr) * 32 + kg;
  int brdo = (wn + fr) * 32 + kg;

  auto STAGE = [&](int buf, int k0) {
    GLDS(Ag + k0, As + buf * 4096 + wbase);
    GLDS(Bg + k0, Bs + buf * 4096 + wbase);
  };

  STAGE(0, kbase);
  __syncthreads();
  int cur = 0;
  for (int k0 = kbase; k0 < kend; k0 += 32) {
    int nxt = k0 + 32;
    if (nxt < kend) STAGE(cur ^ 1, nxt);
    const u16* Ard = As + cur * 4096 + ardo;
    const u16* Brd = Bs + cur * 4096 + brdo;
    s16x8 aF[4], bF[2];
    #pragma unroll
    for (int m = 0; m < 4; ++m) aF[m] = *(const s16x8*)(Ard + m * 16 * 32);
    #pragma unroll
    for (int n = 0; n < 2; ++n) bF[n] = *(const s16x8*)(Brd + n * 16 * 32);
    #pragma unroll
    for (int m = 0; m < 4; ++m)
      #pragma unroll
      for (int n = 0; n < 2; ++n)
        acc[m][n] = __builtin_amdgcn_mfma_f32_16x16x32_bf16(aF[m], bF[n], acc[m][n], 0, 0, 0);
    __syncthreads();
    cur ^= 1;
  }

  float* Cpart = (blockIdx.z == 0) ? Cf : ((blockIdx.z == 1) ? Cf2 : ((blockIdx.z == 2) ? Cf3 : Cf4));
  int fq = (lane >> 4) << 2;
  #pragma unroll
  for (int n = 0; n < 2; ++n) {
    int col = col0 + wn + n * 16 + fr;
    float bs = bias ? bias[col] : 0.f;
    #pragma unroll
    for (int m = 0; m < 4; ++m) {
      float v[4];
      #pragma unroll
      for (int r = 0; r < 4; ++r) {
        v[r] = acc[m][n][r] + bs;
        if (relu) v[r] = fmaxf(v[r], 0.f);
      }
      int rowb = row0 + wm + m * 16 + fq;
      if (mode == 0) {
        if (Cpart) {
          #pragma unroll
          for (int r = 0; r < 4; ++r) Cpart[(size_t)(rowb + r) * N + col] = v[r];
        }
        if (Cb) {
          #pragma unroll
          for (int r = 0; r < 4; ++r) Cb[(size_t)(rowb + r) * N + col] = f2bf(v[r]);
        }
      } else {
        int q = col >> 10, lc = col & 1023;
        u16* dstRM = nullptr;
        if (mode == 1) dstRM = (q == 0) ? Cb : ((q == 1) ? Cb2 : nullptr);
        else           dstRM = (q == 0) ? Cb : nullptr;
        if (dstRM) {
          #pragma unroll
          for (int r = 0; r < 4; ++r) dstRM[(size_t)(rowb + r) * 1024 + lc] = f2bf(v[r]);
        } else {
          u16 pb[4] = { f2bf(v[0]), f2bf(v[1]), f2bf(v[2]), f2bf(v[3]) };
          uint2 wv; wv.x = (u32)pb[0] | ((u32)pb[1] << 16); wv.y = (u32)pb[2] | ((u32)pb[3] << 16);
          *(uint2*)(Ct + (size_t)lc * 4096 + rowb) = wv;
        }
      }
    }
  }
}

// ---------------- stage 64x64 bf16 (global pitch gp) -> padded LDS [64][72] ----------------
static __device__ __forceinline__ void stage_pad(const u16* __restrict__ g, int gp, u16* L, int tid) {
  #pragma unroll
  for (int i = 0; i < 2; ++i) {
    int c = (i << 8) + tid;                 // 0..511 chunks of 8
    int row = c >> 3, col8 = (c & 7) << 3;
    uint4 v = *(const uint4*)(g + (size_t)row * gp + col8);
    *(uint4*)(L + row * 72 + col8) = v;
  }
}

// ---------------- attention pass 1 (MFMA): per-(bh,s) max & sum over t ----------------
__global__ __launch_bounds__(256) void k_attn_stats_mfma(const u16* __restrict__ Qb, const u16* __restrict__ Kb,
                                                         float* __restrict__ cmax, float* __restrict__ csum) {
  __shared__ u16 Ks[64 * 72];
  __shared__ u16 Qs[64 * 72];
  int tid = threadIdx.x, wave = tid >> 6, lane = tid & 63;
  int bh = blockIdx.x, b = bh >> 4, h = bh & 15;
  int s0 = blockIdx.y << 6;
  stage_pad(Kb + ((size_t)(b * TT + s0)) * DD + h * 64, DD, Ks, tid);
  __syncthreads();
  int fr = lane & 15, g = lane >> 4;
  const u16* Bbase = Ks + (wave * 16 + fr) * 72 + g * 8;
  const u16* Abase = Qs + fr * 72 + g * 8;
  s16x8 bF0 = *(const s16x8*)(Bbase);
  s16x8 bF1 = *(const s16x8*)(Bbase + 32);
  float m = -1e30f, sum = 0.f;
  for (int t0 = 0; t0 < TT; t0 += 64) {
    __syncthreads();
    stage_pad(Qb + ((size_t)(b * TT + t0)) * DD + h * 64, DD, Qs, tid);
    __syncthreads();
    #pragma unroll
    for (int mt = 0; mt < 4; ++mt) {
      f32x4 acc = f32x4{0.f, 0.f, 0.f, 0.f};
      s16x8 a0 = *(const s16x8*)(Abase + mt * 16 * 72);
      s16x8 a1 = *(const s16x8*)(Abase + mt * 16 * 72 + 32);
      acc = __builtin_amdgcn_mfma_f32_16x16x32_bf16(a0, bF0, acc, 0, 0, 0);
      acc = __builtin_amdgcn_mfma_f32_16x16x32_bf16(a1, bF1, acc, 0, 0, 0);
      float v0 = acc[0] * 0.125f, v1 = acc[1] * 0.125f, v2 = acc[2] * 0.125f, v3 = acc[3] * 0.125f;
      float tm = fmaxf(fmaxf(v0, v1), fmaxf(v2, v3));
      float nm = fmaxf(m, tm);
      sum = sum * __expf(m - nm) + __expf(v0 - nm) + __expf(v1 - nm) + __expf(v2 - nm) + __expf(v3 - nm);
      m = nm;
    }
  }
  #pragma unroll
  for (int mask = 16; mask <= 32; mask <<= 1) {
    float m2 = __shfl_xor(m, mask, 64);
    float s2 = __shfl_xor(sum, mask, 64);
    float nm = fmaxf(m, m2);
    sum = sum * __expf(m - nm) + s2 * __expf(m2 - nm);
    m = nm;
  }
  if (lane < 16) {
    size_t o = (size_t)bh * TT + s0 + wave * 16 + lane;
    cmax[o] = m; csum[o] = sum;
  }
}

// ---------------- attention pass 2 (MFMA) ----------------
__global__ __launch_bounds__(256) void k_attn_apply_mfma(const u16* __restrict__ Qb, const u16* __restrict__ Kb,
                                                         const u16* __restrict__ Vt,
                                                         const float* __restrict__ cmax, const float* __restrict__ csum,
                                                         u16* __restrict__ Op) {
  __shared__ u16 Qs[64 * 72];
  __shared__ u16 Ks[64 * 72];
  __shared__ u16 VTs[64 * 72];
  __shared__ u16 Pl[4 * 1024];
  __shared__ float cmL[64];
  __shared__ float rcsL[64];
  int tid = threadIdx.x, wave = tid >> 6, lane = tid & 63;
  int bh = blockIdx.x, b = bh >> 4, h = bh & 15;
  int t0 = blockIdx.y << 6;
  stage_pad(Qb + ((size_t)(b * TT + t0)) * DD + h * 64, DD, Qs, tid);
  __syncthreads();
  int fr = lane & 15, g = lane >> 4;
  const u16* QbF = Qs + (wave * 16 + fr) * 72 + g * 8;
  const u16* KaF = Ks + fr * 72 + g * 8;
  char* Pw = (char*)(Pl + wave * 1024);
  uint swz = ((uint)(lane & 7)) << 4;
  s16x8 qF0 = *(const s16x8*)(QbF);
  s16x8 qF1 = *(const s16x8*)(QbF + 32);
  f32x4 acc_o[4];
  #pragma unroll
  for (int nt = 0; nt < 4; ++nt) acc_o[nt] = f32x4{0.f, 0.f, 0.f, 0.f};
  const size_t cbase = (size_t)bh * TT;

  for (int s0 = 0; s0 < TT; s0 += 64) {
    __syncthreads();
    stage_pad(Kb + ((size_t)(b * TT + s0)) * DD + h * 64, DD, Ks, tid);
    stage_pad(Vt + (size_t)(h * 64) * 4096 + (size_t)b * TT + s0, 4096, VTs, tid);
    if (tid < 64) cmL[tid] = cmax[cbase + s0 + tid];
    else if (tid < 128) rcsL[tid - 64] = 1.f / csum[cbase + s0 + tid - 64];
    __syncthreads();
    #pragma unroll
    for (int mt = 0; mt < 4; ++mt) {
      f32x4 acc = f32x4{0.f, 0.f, 0.f, 0.f};
      s16x8 a0 = *(const s16x8*)(KaF + mt * 16 * 72);
      s16x8 a1 = *(const s16x8*)(KaF + mt * 16 * 72 + 32);
      acc = __builtin_amdgcn_mfma_f32_16x16x32_bf16(a0, qF0, acc, 0, 0, 0);
      acc = __builtin_amdgcn_mfma_f32_16x16x32_bf16(a1, qF1, acc, 0, 0, 0);
      f32x4 cm4 = *(const f32x4*)&cmL[mt * 16 + g * 4];
      f32x4 rc4 = *(const f32x4*)&rcsL[mt * 16 + g * 4];
      u16 pb[4];
      #pragma unroll
      for (int r = 0; r < 4; ++r)
        pb[r] = f2bf(__expf(acc[r] * 0.125f - cm4[r]) * rc4[r]);
      uint woff = (uint)fr * 128 + (uint)(mt * 16 + g * 4) * 2;
      uint2 wv; wv.x = (u32)pb[0] | ((u32)pb[1] << 16); wv.y = (u32)pb[2] | ((u32)pb[3] << 16);
      *(uint2*)(Pw + (woff ^ swz)) = wv;
    }
    uint rbase = (uint)fr * 128;
    s16x8 pF0 = *(const s16x8*)(Pw + ((rbase + g * 16) ^ swz));
    s16x8 pF1 = *(const s16x8*)(Pw + ((rbase + 64 + g * 16) ^ swz));
    #pragma unroll
    for (int nt = 0; nt < 4; ++nt) {
      s16x8 v0 = *(const s16x8*)(VTs + (nt * 16 + fr) * 72 + g * 8);
      s16x8 v1 = *(const s16x8*)(VTs + (nt * 16 + fr) * 72 + 32 + g * 8);
      acc_o[nt] = __builtin_amdgcn_mfma_f32_16x16x32_bf16(pF0, v0, acc_o[nt], 0, 0, 0);
      acc_o[nt] = __builtin_amdgcn_mfma_f32_16x16x32_bf16(pF1, v1, acc_o[nt], 0, 0, 0);
    }
  }
  int tg = t0 + wave * 16 + g * 4;
  #pragma unroll
  for (int nt = 0; nt < 4; ++nt) {
    #pragma unroll
    for (int r = 0; r < 4; ++r) {
      Op[((size_t)(b * TT + tg + r)) * DD + h * 64 + nt * 16 + fr] = f2bf(acc_o[nt][r]);
    }
  }
}

// ---------------- O = norm(sum of partials + bias + residual), ddof=1 ----------------
__global__ __launch_bounds__(256) void k_add_norm(const float* __restrict__ A, const float* __restrict__ A2,
                                                  const float* __restrict__ A3, const float* __restrict__ A4,
                                                  const float* __restrict__ bias,
                                                  const float* __restrict__ Bv,
                                                  float* __restrict__ O, u16* __restrict__ Ob) {
  int row = blockIdx.x, tid = threadIdx.x;
  size_t base = (size_t)row * DD;
  __shared__ float red[256];
  float v[4]; float s = 0.f;
  #pragma unroll
  for (int i = 0; i < 4; ++i) {
    int c = tid + (i << 8);
    float t = A[base + c] + Bv[base + c];
    if (A2) t += A2[base + c];
    if (A3) t += A3[base + c];
    if (A4) t += A4[base + c];
    if (bias) t += bias[c];
    v[i] = t; s += t;
  }
  red[tid] = s; __syncthreads();
  for (int t = 128; t > 0; t >>= 1) { if (tid < t) red[tid] += red[tid + t]; __syncthreads(); }
  float mean = red[0] * (1.f / 1024.f);
  __syncthreads();
  float vs = 0.f;
  #pragma unroll
  for (int i = 0; i < 4; ++i) { float d = v[i] - mean; vs += d * d; }
  red[tid] = vs; __syncthreads();
  for (int t = 128; t > 0; t >>= 1) { if (tid < t) red[tid] += red[tid + t]; __syncthreads(); }
  float inv = rsqrtf(red[0] * (1.f / 1023.f));
  #pragma unroll
  for (int i = 0; i < 4; ++i) {
    float o = (v[i] - mean) * inv;
    O[base + tid + (i << 8)] = o;
    if (Ob) Ob[base + tid + (i << 8)] = f2bf(o);
  }
}

extern "C" void kernel_launch(void* const* d_in, const int* in_sizes, int n_in,
                              void* d_out, int out_size, void* d_ws, size_t ws_size,
                              hipStream_t stream) {
  (void)in_sizes; (void)n_in; (void)out_size; (void)ws_size;
  const float* x    = (const float*)d_in[0];
  const float* y    = (const float*)d_in[1];
  const float* Wq1  = (const float*)d_in[2];
  const float* Wk1  = (const float*)d_in[3];
  const float* Wv1  = (const float*)d_in[4];
  const float* Wo1  = (const float*)d_in[5];
  const float* Wq2  = (const float*)d_in[6];
  const float* Wk2  = (const float*)d_in[7];
  const float* Wv2  = (const float*)d_in[8];
  const float* Wo2  = (const float*)d_in[9];
  const float* w_in  = (const float*)d_in[10];
  const float* b_in  = (const float*)d_in[11];
  const float* w_out = (const float*)d_in[12];
  const float* b_out = (const float*)d_in[13];

  float* ws = (float*)d_ws;
  size_t off = 0;
  auto allocw = [&](size_t nw) { float* p = ws + off; off += nw; return p; };
  const size_t MR = (size_t)BB * TT;           // 4096
  const size_t ND = MR * DD;                   // 4.19M elems

  u16* Bq   = (u16*)allocw(512 * 1024);        // Bq|Bk|Bv contiguous => fused B (3072 x 1024)
  u16* Bk   = (u16*)allocw(512 * 1024);
  u16* Bv   = (u16*)allocw(512 * 1024);
  u16* Bwo  = (u16*)allocw(512 * 1024);
  u16* Wi   = (u16*)allocw(2 * 1024 * 1024);
  u16* Wob  = (u16*)allocw(2 * 1024 * 1024);
  u16* xbf  = (u16*)allocw(ND / 2);            // xbf|ybf span also = f32 partial (FF2 slice 3)
  u16* ybf  = (u16*)allocw(ND / 2);
  u16* REG  = (u16*)allocw(ND * 2);
  float* ff2  = allocw(ND);
  float* out1 = allocw(ND);
  float* out2 = allocw(ND);
  float* cmax = allocw((size_t)BB * HH * TT);
  float* csum = allocw((size_t)BB * HH * TT);

  u16* Qb = REG;
  u16* Kb = REG + ND;
  u16* Vt = REG + 2 * ND;   // V col-major (1024 x 4096), pitch 4096
  u16* Mb = REG + 3 * ND;   // mhaO; also out1_bf between layers
  u16* ff1b = REG;
  u16* out2bf = ybf;
  float* doutHi = (float*)d_out + ND;  // free until final add_norm writes it
  float* pXY = (float*)xbf;            // xbf+ybf span (dead after L2 KV proj / FF1)

  dim3 blk(256), blkG(512);
  dim3 gConv(4096);
  dim3 gSm(1024);
  dim3 gRw(16, 16);
  dim3 gQKV(24, 32);         // N=3072
  dim3 gKV(16, 32);          // N=2048
  dim3 gP(8, 32);            // N=1024, no split
  dim3 gP2(8, 32, 2);        // N=1024, split-K=2
  dim3 gF1(32, 32);          // N=4096
  dim3 gFF2(8, 32, 4);       // N=1024, split-K=4 (K=4096)
  dim3 gAttn(BB * HH, TT / 64);
  dim3 gNorm(MR);

  hipMemcpyAsync(d_out, (const void*)x, ND * sizeof(float), hipMemcpyDeviceToDevice, stream);

  k_f2bf<<<gConv, blk, 0, stream>>>(y, ybf, (int)ND);
  k_f2bf<<<gConv, blk, 0, stream>>>(x, xbf, (int)ND);
  k_f2bf<<<gConv, blk, 0, stream>>>(w_in, Wi, FFF * DD);
  k_f2bf<<<gConv, blk, 0, stream>>>(w_out, Wob, DD * FFF);

  // ---- Layer 1: masked self-attention on y ----
  k_softmax_w_bf<<<gSm, blk, 0, stream>>>(Wq1, Bq);
  k_softmax_w_bf<<<gSm, blk, 0, stream>>>(Wk1, Bk);
  k_reorder_w_bf<<<gRw, blk, 0, stream>>>(Wv1, Bv);
  k_transpose_bf<<<gRw, blk, 0, stream>>>(Wo1, Bwo);
  k_mfma_nt<<<gQKV, blkG, 0, stream>>>(ybf, Bq, nullptr, nullptr, nullptr, nullptr, Qb, Kb, Vt, nullptr, 0, 1, 4096, 3072, 1024);
  k_attn_stats_mfma<<<gAttn, blk, 0, stream>>>(Qb, Kb, cmax, csum);
  k_attn_apply_mfma<<<gAttn, blk, 0, stream>>>(Qb, Kb, Vt, cmax, csum, Mb);
  // out-proj split-K=2: partials ff2 + out2 (out2 unused until layer 2)
  k_mfma_nt<<<gP2, blkG, 0, stream>>>(Mb, Bwo, ff2, out2, nullptr, nullptr, nullptr, nullptr, nullptr, nullptr, 0, 0, 4096, 1024, 1024);
  k_add_norm<<<gNorm, blk, 0, stream>>>(ff2, out2, nullptr, nullptr, nullptr, y, out1, Mb /* out1_bf */);

  // ---- Layer 2: cross-attention (Q from out1, K/V from x) ----
  k_reorder_w_bf<<<gRw, blk, 0, stream>>>(Wq2, Bq);
  k_reorder_w_bf<<<gRw, blk, 0, stream>>>(Wk2, Bk);
  k_reorder_w_bf<<<gRw, blk, 0, stream>>>(Wv2, Bv);
  k_transpose_bf<<<gRw, blk, 0, stream>>>(Wo2, Bwo);
  k_mfma_nt<<<gP, blkG, 0, stream>>>(Mb /* out1_bf */, Bq, nullptr, nullptr, nullptr, nullptr, Qb, nullptr, nullptr, nullptr, 0, 0, 4096, 1024, 1024);
  k_mfma_nt<<<gKV, blkG, 0, stream>>>(xbf, Bk, nullptr, nullptr, nullptr, nullptr, Kb, nullptr, Vt, nullptr, 0, 2, 4096, 2048, 1024);
  k_attn_stats_mfma<<<gAttn, blk, 0, stream>>>(Qb, Kb, cmax, csum);
  k_attn_apply_mfma<<<gAttn, blk, 0, stream>>>(Qb, Kb, Vt, cmax, csum, Mb);
  // out-proj split-K=2: partials ff2 + doutHi (d_out upper half free until final norm)
  k_mfma_nt<<<gP2, blkG, 0, stream>>>(Mb, Bwo, ff2, doutHi, nullptr, nullptr, nullptr, nullptr, nullptr, nullptr, 0, 0, 4096, 1024, 1024);
  k_add_norm<<<gNorm, blk, 0, stream>>>(ff2, doutHi, nullptr, nullptr, nullptr, out1, out2, out2bf);

  // ---- FF ----
  k_mfma_nt<<<gF1, blkG, 0, stream>>>(out2bf, Wi, nullptr, nullptr, nullptr, nullptr, ff1b, nullptr, nullptr, b_in, 1, 0, 4096, 4096, 1024);
  // FF2 split-K=4: partials ff2, doutHi, out1, pXY (all dead at this point)
  k_mfma_nt<<<gFF2, blkG, 0, stream>>>(ff1b, Wob, ff2, doutHi, out1, pXY, nullptr, nullptr, nullptr, nullptr, 0, 0, 4096, 1024, 4096);
  k_add_norm<<<gNorm, blk, 0, stream>>>(ff2, doutHi, out1, pXY, b_out, out2, doutHi, nullptr);
}